// Round 4
// baseline (636.815 us; speedup 1.0000x reference)
//
#include <hip/hip_runtime.h>
#include <stdint.h>

#define N_ROWS 512
#define D_IN 1024
#define ZCAT_COLS 2342
#define S_TOT 117660
#define S_PAD 117760
#define J_SLM 170000
#define J_WSD 107660

// Centers for bf16 residual storage of per-n constants (exact part goes via fp32 EP[s]).
#define C8f  (-18.49f)   // C3w
#define C17f (-18.95f)   // C3s
#define C18f (-6.91f)    // -lseHS
#define C19f (-14.51f)   // A1s
#define C20f (-15.76f)   // A2s
#define C21f (-6.91f)    // -lseHW
#define C22f (-14.51f)   // A1w
#define C23f (-15.76f)   // A2w

typedef __attribute__((ext_vector_type(8))) short short8;
typedef __attribute__((ext_vector_type(4))) float f32x4;

__device__ inline unsigned short f2bf(float f){
  unsigned int u = __float_as_uint(f);
  u += 0x7FFF + ((u >> 16) & 1);
  return (unsigned short)(u >> 16);
}

// ---------------- merged prep: bn partials | tail-3 moments | per-sense q build ----------------
// blocks [0,64): BN partial sums; [64,128): moments; [128,588): build_q. All independent.
__global__ __launch_bounds__(256) void prep_kernel(
  const float* __restrict__ x, float* __restrict__ colacc,
  const float* __restrict__ wS, const float* __restrict__ wW, float* __restrict__ mom,
  const int* __restrict__ sv_cols, const float* __restrict__ sv_vals,
  unsigned short* __restrict__ qbf, float* __restrict__ EP, int* __restrict__ nsm,
  uint2* __restrict__ cv)
{
  int b = blockIdx.x;
  __shared__ float lds[4][72];
  if (b < 64){
    // ---- BN partial sums ----
    int r0 = b * 8;
    int t = threadIdx.x;
    #pragma unroll
    for (int q = 0; q < 4; q++){
      int j = t + q * 256;
      float s1 = 0.f, s2 = 0.f;
      #pragma unroll
      for (int r = 0; r < 8; r++){
        float v = x[(size_t)(r0 + r) * D_IN + j];
        s1 += v; s2 += v * v;
      }
      atomicAdd(&colacc[j], s1);
      atomicAdd(&colacc[1024 + j], s2);
    }
    return;
  }
  if (b < 128){
    // ---- moments: 32 x-blocks per side ----
    int bb = b - 64;
    int side = bb >> 5;          // 0: SLM(wS), 1: WSD(wW)
    int xb = bb & 31;
    const float* w2 = side ? wW : wS;
    int J = side ? J_WSD : J_SLM;
    float* outp = mom + side * 72;
    float s1[8]; float m2[64];
    #pragma unroll
    for (int e = 0; e < 8; e++) s1[e] = 0.f;
    #pragma unroll
    for (int e = 0; e < 64; e++) m2[e] = 0.f;
    for (int r = xb * 256 + threadIdx.x; r < J; r += 32 * 256){
      const f32x4* p = (const f32x4*)(w2 + (size_t)r * 8);
      f32x4 wa = p[0], wb = p[1];
      float w[8] = {wa[0], wa[1], wa[2], wa[3], wb[0], wb[1], wb[2], wb[3]};
      #pragma unroll
      for (int a = 0; a < 8; a++){
        s1[a] += w[a];
        #pragma unroll
        for (int bq = 0; bq < 8; bq++) m2[a * 8 + bq] += w[a] * w[bq];
      }
    }
    int L = threadIdx.x & 63; int wave = threadIdx.x >> 6;
    #pragma unroll
    for (int e = 0; e < 72; e++){
      float v = (e < 8) ? s1[e] : m2[e - 8];
      #pragma unroll
      for (int d = 32; d > 0; d >>= 1) v += __shfl_down(v, d);
      if (L == 0) lds[wave][e] = v;
    }
    __syncthreads();
    int tt = threadIdx.x;
    if (tt < 72){
      float v = lds[0][tt] + lds[1][tt] + lds[2][tt] + lds[3][tt];
      atomicAdd(&outp[tt], v);
    }
    return;
  }
  // ---- build_q ----
  int s = (b - 128) * 256 + threadIdx.x;
  if (s >= S_PAD) return;
  unsigned short qr[32];
  #pragma unroll
  for (int e = 0; e < 32; e++) qr[e] = 0;
  uint2 pairs[10];
  #pragma unroll
  for (int e = 0; e < 10; e++){ pairs[e].x = 0; pairs[e].y = 0; }
  int idx = 0; float cw = 0.f, vh = 0.f, v1s = 0.f, v2s = 0.f;
  float w8[8];
  #pragma unroll
  for (int e = 0; e < 8; e++) w8[e] = 0.f;
  if (s < S_TOT){
    if (s < 10000){ pairs[0].x = (unsigned)(10000 + s); pairs[0].y = __float_as_uint(1.0f); idx = 1; }
    #pragma unroll
    for (int k = 0; k < 8; k++){
      int c = sv_cols[(size_t)s * 8 + k];
      float v = 0.1f * sv_vals[(size_t)s * 8 + k];
      if (c >= 10000){
        cw += v;
        const float* wr = wS + (size_t)(c - 10000) * 8;
        #pragma unroll
        for (int j = 0; j < 8; j++) w8[j] += v * wr[j];
      } else {
        pairs[idx].x = (unsigned)c; pairs[idx].y = __float_as_uint(v); idx++;
        if (c < 1000) vh += v; else if (c < 3000) v1s += v; else v2s += v;
      }
    }
    if (s >= 10000){
      const float* wrw = wW + (size_t)(s - 10000) * 8;
      #pragma unroll
      for (int j = 0; j < 8; j++) qr[j] = f2bf(wrw[j]);
      qr[8] = f2bf(1.0f);
    }
    #pragma unroll
    for (int j = 0; j < 8; j++) qr[9 + j] = f2bf(w8[j]);
    qr[17] = f2bf(cw); qr[18] = f2bf(vh); qr[19] = f2bf(v1s); qr[20] = f2bf(v2s);
    qr[21] = f2bf(s < 1000 ? 1.f : 0.f);
    qr[22] = f2bf((s >= 1000 && s < 3000) ? 1.f : 0.f);
    qr[23] = f2bf((s >= 3000 && s < 10000) ? 1.f : 0.f);
    float ep = (s >= 10000) ? C8f : (s < 1000 ? C21f : (s < 3000 ? C22f : C23f));
    ep += cw * C17f + vh * C18f + v1s * C19f + v2s * C20f;
    EP[s] = ep;
  } else {
    EP[s] = 0.f;
  }
  nsm[s] = idx;
  #pragma unroll
  for (int e = 0; e < 10; e++) cv[(size_t)s * 10 + e] = pairs[e];
  short8* qp = (short8*)(qbf + (size_t)s * 32);
  const short8* src = (const short8*)qr;
  qp[0] = src[0]; qp[1] = src[1]; qp[2] = src[2]; qp[3] = src[3];
}

// ---------------- fp32 -> bf16 conversion of everything (BN finalize inlined) ----------------
__global__ void convert_all(
  const float* __restrict__ x, const float* __restrict__ colacc,
  const float* __restrict__ gamma, const float* __restrict__ beta, unsigned short* __restrict__ xbn,
  const float* __restrict__ dw, unsigned short* __restrict__ dwb,
  const float* __restrict__ h1w, unsigned short* __restrict__ h1b,
  const float* __restrict__ h2w, unsigned short* __restrict__ h2b,
  const float* __restrict__ sh, const float* __restrict__ wh,
  const float* __restrict__ s11, const float* __restrict__ w11,
  const float* __restrict__ s21, const float* __restrict__ w21,
  const float* __restrict__ s31, const float* __restrict__ w31, unsigned short* __restrict__ wcat,
  const float* __restrict__ st1w2, unsigned short* __restrict__ st1b,
  const float* __restrict__ wt1w2, unsigned short* __restrict__ wt1b,
  const float* __restrict__ st2w2, unsigned short* __restrict__ st2b,
  const float* __restrict__ wt2w2, unsigned short* __restrict__ wt2b)
{
  size_t i = (size_t)blockIdx.x * 256 + threadIdx.x;
  const size_t o1 = 524288, o2 = o1 + 524288, o3 = o2 + 262144, o4 = o3 + 262144,
               o5 = o4 + 1199104, o6 = o5 + 256000, o7 = o6 + 256000, o8 = o7 + 224000,
               o9 = o8 + 224000;
  if (i < o1){
    int c = (int)(i & 1023);
    float mu = colacc[c] * (1.0f / 512.0f);
    float var = colacc[1024 + c] * (1.0f / 512.0f) - mu * mu;
    float sc = rsqrtf(var + 1e-5f) * gamma[c];
    float shv = beta[c] - mu * sc;
    xbn[i] = f2bf(x[i] * sc + shv);
  }
  else if (i < o2){ size_t l = i - o1; dwb[l] = f2bf(dw[l]); }
  else if (i < o3){ size_t l = i - o2; h1b[l] = f2bf(h1w[l]); }
  else if (i < o4){ size_t l = i - o3; h2b[l] = f2bf(h2w[l]); }
  else if (i < o5){
    size_t l = i - o4;
    float v;
    if (l < 513536) v = sh[l];
    else if (l < 1027072) v = wh[l - 513536];
    else if (l < 1092608) v = s11[l - 1027072];
    else if (l < 1158144) v = w11[l - 1092608];
    else if (l < 1174528) v = s21[l - 1158144];
    else if (l < 1190912) v = w21[l - 1174528];
    else if (l < 1195008) v = s31[l - 1190912];
    else v = w31[l - 1195008];
    wcat[l] = f2bf(v);
  }
  else if (i < o6){ size_t l = i - o5; st1b[l] = f2bf(st1w2[l]); }
  else if (i < o7){ size_t l = i - o6; wt1b[l] = f2bf(wt1w2[l]); }
  else if (i < o8){ size_t l = i - o7; st2b[l] = f2bf(st2w2[l]); }
  else if (i < o9){ size_t l = i - o8; wt2b[l] = f2bf(wt2w2[l]); }
}

// ---------------- MLP NT bf16 MFMA GEMM: C[m,n] = sum_k A[m,k]*B[n,k] -> bf16 ----------------
__global__ __launch_bounds__(256) void gemm_mlp(
  const unsigned short* __restrict__ A, int lda, const unsigned short* __restrict__ B,
  const float* __restrict__ bias, unsigned short* __restrict__ outB,
  int N, int K, int relu)
{
  int t = threadIdx.x; int wave = t >> 6; int L = t & 63; int quad = L >> 4; int l16 = L & 15;
  int mbase = blockIdx.y * 64 + wave * 16;
  int nb0 = blockIdx.x * 16;
  f32x4 acc = {0,0,0,0};
  int mrow = mbase + l16;
  const unsigned short* Ap = A + (size_t)mrow * lda + quad * 8;
  int nn = nb0 + l16;
  if (nn > N - 1) nn = N - 1;
  const unsigned short* Bp = B + (size_t)nn * K + quad * 8;
  for (int k0 = 0; k0 < K; k0 += 32){
    short8 a = *(const short8*)(Ap + k0);
    short8 b = *(const short8*)(Bp + k0);
    acc = __builtin_amdgcn_mfma_f32_16x16x32_bf16(a, b, acc, 0, 0, 0);
  }
  int n = nb0 + l16;
  if (n < N){
    float bv = bias ? bias[n] : 0.0f;
    #pragma unroll
    for (int r = 0; r < 4; r++){
      int m = mbase + quad * 4 + r;
      float v = acc[r] + bv;
      if (relu) v = fmaxf(v, 0.0f);
      outB[(size_t)m * N + n] = f2bf(v);
    }
  }
}

// ---------------- Zcat GEMM + head exp-sums + htcat + FUSED head transpose into smallT ----------
// Block tile = 16 cols x 64 m-rows. Head cols (c<1000 S-side, 1003<=c<2003 W-side) are
// transposed via LDS and written directly into smallT (kills the old build_smallT head pass).
// Zcat fp32 writes restricted to the 22 columns the finals kernel actually reads.
__global__ __launch_bounds__(256) void gemm_zcat(
  const unsigned short* __restrict__ A, const unsigned short* __restrict__ B,
  float* __restrict__ Zcat, unsigned short* __restrict__ htcat, float* __restrict__ sums6,
  float* __restrict__ smallT)
{
  const int N = ZCAT_COLS, K = 512;
  int t = threadIdx.x; int wave = t >> 6; int L = t & 63; int quad = L >> 4; int l16 = L & 15;
  int mbase = blockIdx.y * 64 + wave * 16;
  int nb0 = blockIdx.x * 16;
  f32x4 acc = {0,0,0,0};
  int mrow = mbase + l16;
  const unsigned short* Ap = A + (size_t)mrow * 512 + quad * 8;
  int nn = nb0 + l16;
  if (nn > N - 1) nn = N - 1;
  const unsigned short* Bp = B + (size_t)nn * K + quad * 8;
  for (int k0 = 0; k0 < K; k0 += 32){
    short8 a = *(const short8*)(Ap + k0);
    short8 b = *(const short8*)(Bp + k0);
    acc = __builtin_amdgcn_mfma_f32_16x16x32_bf16(a, b, acc, 0, 0, 0);
  }
  bool doEps = (nb0 < 2006);
  __shared__ float sacc[64][2];
  __shared__ float tile[16][65];
  if (doEps){
    for (int e = threadIdx.x; e < 128; e += 256) ((float*)sacc)[e] = 0.f;
    __syncthreads();
  }
  int c = nb0 + l16;
  #pragma unroll
  for (int r = 0; r < 4; r++){
    int m = mbase + quad * 4 + r;
    float v = acc[r];
    if (c < N){
      bool zkeep = (c >= 1000 && c < 1003) || (c >= 2003 && c < 2006) || (c >= 2326);
      if (zkeep) Zcat[(size_t)m * ZCAT_COLS + c] = v;
      if (c >= 2006) htcat[(size_t)m * 336 + (c - 2006)] = f2bf(v);
    }
    if (doEps){
      float e0 = (c < 1003) ? __expf(v) : 0.f;
      float e1 = (c >= 1003 && c < 2006) ? __expf(v) : 0.f;
      #pragma unroll
      for (int d = 8; d > 0; d >>= 1){ e0 += __shfl_xor(e0, d); e1 += __shfl_xor(e1, d); }
      if (l16 == 0){
        int mr = wave * 16 + quad * 4 + r;
        if (e0 != 0.f) atomicAdd(&sacc[mr][0], e0);
        if (e1 != 0.f) atomicAdd(&sacc[mr][1], e1);
      }
    }
  }
  bool doT = (nb0 < 2003);   // block-uniform
  if (doT){
    #pragma unroll
    for (int r = 0; r < 4; r++)
      tile[l16][wave * 16 + quad * 4 + r] = acc[r];
    __syncthreads();
    int tlo = t & 63, thi = t >> 6;
    int m0 = blockIdx.y * 64;
    #pragma unroll
    for (int p = 0; p < 4; p++){
      int cl = thi + p * 4;
      int cg = nb0 + cl;
      int row = -1;
      if (cg < 1000) row = cg;                              // S-side head
      else if (cg >= 1003 && cg < 2003) row = 10000 + (cg - 1003);  // W-side head
      if (row >= 0) smallT[(size_t)row * 512 + m0 + tlo] = tile[cl][tlo];
    }
  }
  if (doEps){
    __syncthreads();
    int tt = threadIdx.x;
    if (tt < 128){
      int mr = tt >> 1;
      float v = sacc[mr][tt & 1];
      if (v != 0.f) atomicAdd(&sums6[(blockIdx.y * 64 + mr) * 8 + (tt & 1)], v);
    }
  }
}

// ---------------- merged tail GEMMs + exp-sums + FUSED transposed write into smallT ----------------
// Flattened grid: bx in [0,32) zi=0; [32,64) zi=1; [64,174) zi=2; [174,284) zi=3 (no dead blocks).
// smallT row bases: z1S->1000, z1W->11000, z2S->3000, z2W->13000.
__global__ __launch_bounds__(256) void gemm_tail(
  const unsigned short* __restrict__ htcat,
  const unsigned short* __restrict__ b0, const unsigned short* __restrict__ b1,
  const unsigned short* __restrict__ b2, const unsigned short* __restrict__ b3,
  float* __restrict__ smallT, float* __restrict__ sums6)
{
  int bx = blockIdx.x;
  int zi, nbx;
  if (bx < 32){ zi = 0; nbx = bx; }
  else if (bx < 64){ zi = 1; nbx = bx - 32; }
  else if (bx < 174){ zi = 2; nbx = bx - 64; }
  else { zi = 3; nbx = bx - 174; }
  int N = (zi < 2) ? 2000 : 7000;
  int K = (zi < 2) ? 128 : 32;
  int aoff = (zi == 0) ? 0 : (zi == 1) ? 128 : (zi == 2) ? 256 : 288;
  int rowbase = (zi == 0) ? 1000 : (zi == 1) ? 11000 : (zi == 2) ? 3000 : 13000;
  const unsigned short* B = (zi == 0) ? b0 : (zi == 1) ? b1 : (zi == 2) ? b2 : b3;
  int nb0 = nbx * 64;
  int t = threadIdx.x; int wave = t >> 6; int L = t & 63; int quad = L >> 4; int l16 = L & 15;
  int mbase = blockIdx.y * 64 + wave * 16;
  f32x4 acc[4] = {{0,0,0,0},{0,0,0,0},{0,0,0,0},{0,0,0,0}};
  int mrow = mbase + l16;
  const unsigned short* Ap = htcat + (size_t)mrow * 336 + aoff + quad * 8;
  const unsigned short* Bp[4];
  #pragma unroll
  for (int j = 0; j < 4; j++){
    int n = nb0 + j * 16 + l16;
    if (n > N - 1) n = N - 1;
    Bp[j] = B + (size_t)n * K + quad * 8;
  }
  for (int k0 = 0; k0 < K; k0 += 32){
    short8 a = *(const short8*)(Ap + k0);
    #pragma unroll
    for (int j = 0; j < 4; j++){
      short8 b = *(const short8*)(Bp[j] + k0);
      acc[j] = __builtin_amdgcn_mfma_f32_16x16x32_bf16(a, b, acc[j], 0, 0, 0);
    }
  }
  __shared__ float sacc[64];
  __shared__ float tile[64][65];
  for (int e = threadIdx.x; e < 64; e += 256) sacc[e] = 0.f;
  __syncthreads();
  #pragma unroll
  for (int j = 0; j < 4; j++){
    int n = nb0 + j * 16 + l16;
    #pragma unroll
    for (int r = 0; r < 4; r++){
      int mloc = wave * 16 + quad * 4 + r;
      float v = acc[j][r];
      tile[j * 16 + l16][mloc] = v;
      float e = (n < N) ? __expf(v) : 0.f;
      #pragma unroll
      for (int d = 8; d > 0; d >>= 1) e += __shfl_xor(e, d);
      if (l16 == 0) atomicAdd(&sacc[mloc], e);
    }
  }
  __syncthreads();
  // transposed write-out: 64 c-rows x 64 m-cols, coalesced along m
  int tlo = t & 63, thi = t >> 6;
  int m0 = blockIdx.y * 64 + tlo;
  #pragma unroll
  for (int p = 0; p < 16; p++){
    int cl = thi + p * 4;
    int cg = nb0 + cl;
    if (cg < N) smallT[(size_t)(rowbase + cg) * 512 + m0] = tile[cl][tlo];
  }
  if (threadIdx.x < 64){
    float v = sacc[threadIdx.x];
    atomicAdd(&sums6[(blockIdx.y * 64 + threadIdx.x) * 8 + 2 + zi], v);
  }
}

// ---------------- per-n finals -> rbf (single block) ----------------
__global__ __launch_bounds__(256) void finals_kernel(const float* __restrict__ Zcat,
                                                     const float* __restrict__ sums6,
                                                     const float* __restrict__ mom,
                                                     unsigned short* __restrict__ rbf){
  for (int n = threadIdx.x; n < 512; n += 256){
    const float* zrow = Zcat + (size_t)n * ZCAT_COLS;
    float lseHS = __logf(sums6[n * 8 + 0]), lseHW = __logf(sums6[n * 8 + 1]);
    float lse1S = __logf(sums6[n * 8 + 2]), lse1W = __logf(sums6[n * 8 + 3]);
    float lse2S = __logf(sums6[n * 8 + 4]), lse2W = __logf(sums6[n * 8 + 5]);
    float uS[8], uW[8];
    #pragma unroll
    for (int j = 0; j < 8; j++){ uS[j] = zrow[2326 + j]; uW[j] = zrow[2334 + j]; }
    const float* mS = mom; const float* mW = mom + 72;
    float d1 = 0.f, d2 = 0.f, e1 = 0.f, e2 = 0.f;
    #pragma unroll
    for (int a = 0; a < 8; a++){
      d1 += uS[a] * mS[a]; e1 += uW[a] * mW[a];
      #pragma unroll
      for (int b = 0; b < 8; b++){
        d2 += uS[a] * uS[b] * mS[8 + a * 8 + b];
        e2 += uW[a] * uW[b] * mW[8 + a * 8 + b];
      }
    }
    float lse3S = __logf((float)J_SLM + d1 + 0.5f * d2);
    float lse3W = __logf((float)J_WSD + e1 + 0.5f * e2);
    float C3w = (zrow[2005] - lseHW) - lse3W;
    float C3s = (zrow[1002] - lseHS) - lse3S;
    float A1s = zrow[1000] - lseHS - lse1S;
    float A2s = zrow[1001] - lseHS - lse2S;
    float A1w = zrow[2003] - lseHW - lse1W;
    float A2w = zrow[2004] - lseHW - lse2W;
    unsigned short* rr = rbf + n * 32;
    #pragma unroll
    for (int j = 0; j < 8; j++){ rr[j] = f2bf(uW[j]); rr[9 + j] = f2bf(uS[j]); }
    rr[8]  = f2bf(C3w - C8f);
    rr[17] = f2bf(C3s - C17f);
    rr[18] = f2bf(-lseHS - C18f);
    rr[19] = f2bf(A1s - C19f);
    rr[20] = f2bf(A2s - C20f);
    rr[21] = f2bf(-lseHW - C21f);
    rr[22] = f2bf(A1w - C22f);
    rr[23] = f2bf(A2w - C23f);
    #pragma unroll
    for (int j = 24; j < 32; j++) rr[j] = 0;
  }
}

// ---------------- the big output kernel ----------------
// Grid (8,460): blockIdx.x (fastest-varying) carries the n-split (prologue re-reads L3-hot).
// out stores are NONTEMPORAL: out (241MB, never re-read) must not thrash smallT (41MB)
// out of L2/L3 — R0 counters showed ~126MB of smallT gathers missing to HBM.
__global__ __launch_bounds__(256, 4) void final2(
  const unsigned short* __restrict__ rbf, const unsigned short* __restrict__ qbf,
  const float* __restrict__ EP, const int* __restrict__ nsm,
  const uint2* __restrict__ cv, const float* __restrict__ smallT,
  float* __restrict__ out)
{
  int t = threadIdx.x; int wave = t >> 6; int L = t & 63; int quad = L >> 4; int l16 = L & 15;
  int sbase = blockIdx.y * 256 + wave * 64;
  int nbase = blockIdx.x * 64;
  short8 bfrag[4]; float ep[4]; int cnt[4]; int kmax[4];
  int ccol[4][3]; float cval[4][3];
  #pragma unroll
  for (int j = 0; j < 4; j++){
    int s = sbase + j * 16 + l16;
    bfrag[j] = *(const short8*)(qbf + (size_t)s * 32 + quad * 8);
    ep[j] = EP[s]; cnt[j] = nsm[s];
    #pragma unroll
    for (int k = 0; k < 3; k++){
      uint2 e = cv[(size_t)s * 10 + k];
      ccol[j][k] = (int)e.x; cval[j][k] = __uint_as_float(e.y);
    }
    int kw = cnt[j];
    #pragma unroll
    for (int d = 32; d > 0; d >>= 1){ int o = __shfl_xor(kw, d); kw = (o > kw) ? o : kw; }
    kmax[j] = __builtin_amdgcn_readfirstlane(kw);
  }
  for (int i = 0; i < 4; i++){
    int n0 = nbase + i * 16;
    short8 afrag = *(const short8*)(rbf + (size_t)(n0 + l16) * 32 + quad * 8);
    int nq = n0 + quad * 4;
    #pragma unroll
    for (int j = 0; j < 4; j++){
      f32x4 acc = {0.f, 0.f, 0.f, 0.f};
      acc = __builtin_amdgcn_mfma_f32_16x16x32_bf16(afrag, bfrag[j], acc, 0, 0, 0);
      f32x4 res = acc + ep[j];
      #pragma unroll
      for (int k = 0; k < 3; k++){
        if (k < kmax[j]){                 // wave-uniform skip
          if (k < cnt[j]){                // per-lane mask
            const f32x4* p = (const f32x4*)(smallT + ((size_t)ccol[j][k] << 9) + nq);
            res += cval[j][k] * (*p);
          }
        }
      }
      if (kmax[j] >= 4){                  // rare overflow path (P ~ 1%)
        int s = sbase + j * 16 + l16;
        for (int k = 3; k < 9; k++){
          if (k < cnt[j]){
            uint2 e = cv[(size_t)s * 10 + k];
            const f32x4* p = (const f32x4*)(smallT + ((size_t)e.x << 9) + nq);
            res += __uint_as_float(e.y) * (*p);
          }
        }
      }
      int sj = sbase + j * 16 + l16;
      if (sj < S_TOT){
        #pragma unroll
        for (int r = 0; r < 4; r++)
          __builtin_nontemporal_store(res[r], &out[(size_t)(nq + r) * S_TOT + sj]);
      }
    }
  }
}

extern "C" void kernel_launch(void* const* d_in, const int* in_sizes, int n_in,
                              void* d_out, int out_size, void* d_ws, size_t ws_size,
                              hipStream_t stream)
{
  const float* x      = (const float*)d_in[0];
  const float* gamma  = (const float*)d_in[1];
  const float* beta   = (const float*)d_in[2];
  const float* dw     = (const float*)d_in[3];
  const float* db     = (const float*)d_in[4];
  const float* h1w    = (const float*)d_in[5];
  const float* h1bias = (const float*)d_in[6];
  const float* h2w    = (const float*)d_in[7];
  const float* h2bias = (const float*)d_in[8];
  const float* whead  = (const float*)d_in[9];
  const float* wt1w1  = (const float*)d_in[10];
  const float* wt1w2  = (const float*)d_in[11];
  const float* wt2w1  = (const float*)d_in[12];
  const float* wt2w2  = (const float*)d_in[13];
  const float* wt3w1  = (const float*)d_in[14];
  const float* wt3w2  = (const float*)d_in[15];
  const float* shead  = (const float*)d_in[16];
  const float* st1w1  = (const float*)d_in[17];
  const float* st1w2  = (const float*)d_in[18];
  const float* st2w1  = (const float*)d_in[19];
  const float* st2w2  = (const float*)d_in[20];
  const float* st3w1  = (const float*)d_in[21];
  const float* st3w2  = (const float*)d_in[22];
  const float* svv    = (const float*)d_in[23];
  const int*   svc    = (const int*)d_in[24];
  float* out = (float*)d_out;

  char* wsb = (char*)d_ws; size_t off = 0;
  auto alloc = [&](size_t bytes) -> void* {
    void* p = wsb + off;
    off = (off + bytes + 255) & ~(size_t)255;
    return p;
  };
  // zero-init region (one memset): colacc | mom | sums6
  float* colacc = (float*)alloc(2048 * 4);
  float* mom    = (float*)alloc(2 * 72 * 4);
  float* sums6  = (float*)alloc(512 * 8 * 4);
  size_t zero_bytes = ((char*)sums6 - (char*)colacc) + 512 * 8 * 4;

  unsigned short* xbn   = (unsigned short*)alloc((size_t)512 * 1024 * 2);
  unsigned short* dwb   = (unsigned short*)alloc((size_t)512 * 1024 * 2);
  unsigned short* h1b   = (unsigned short*)alloc((size_t)512 * 512 * 2);
  unsigned short* h2b   = (unsigned short*)alloc((size_t)512 * 512 * 2);
  unsigned short* wcat  = (unsigned short*)alloc((size_t)ZCAT_COLS * 512 * 2);
  unsigned short* st1b  = (unsigned short*)alloc((size_t)2000 * 128 * 2);
  unsigned short* wt1b  = (unsigned short*)alloc((size_t)2000 * 128 * 2);
  unsigned short* st2b  = (unsigned short*)alloc((size_t)7000 * 32 * 2);
  unsigned short* wt2b  = (unsigned short*)alloc((size_t)7000 * 32 * 2);
  unsigned short* a_bf  = (unsigned short*)alloc((size_t)512 * 512 * 2);
  unsigned short* t_bf  = (unsigned short*)alloc((size_t)512 * 512 * 2);
  unsigned short* h_bf  = (unsigned short*)alloc((size_t)512 * 512 * 2);
  unsigned short* htcat = (unsigned short*)alloc((size_t)512 * 336 * 2);
  float* Zcat  = (float*)alloc((size_t)512 * ZCAT_COLS * 4);
  unsigned short* rbf = (unsigned short*)alloc((size_t)512 * 32 * 2);
  float* smallT = (float*)alloc((size_t)20000 * 512 * 4);
  unsigned short* qbf = (unsigned short*)alloc((size_t)S_PAD * 32 * 2);
  float* EP  = (float*)alloc((size_t)S_PAD * 4);
  int*   nsm = (int*)alloc((size_t)S_PAD * 4);
  uint2* cv  = (uint2*)alloc((size_t)S_PAD * 10 * 8);

  (void)in_sizes; (void)n_in; (void)out_size; (void)ws_size;

  hipMemsetAsync(colacc, 0, zero_bytes, stream);
  prep_kernel<<<588, 256, 0, stream>>>(x, colacc, st3w2, wt3w2, mom,
                                       svc, svv, qbf, EP, nsm, cv);
  convert_all<<<14578, 256, 0, stream>>>(
      x, colacc, gamma, beta, xbn, dw, dwb, h1w, h1b, h2w, h2b,
      shead, whead, st1w1, wt1w1, st2w1, wt2w1, st3w1, wt3w1, wcat,
      st1w2, st1b, wt1w2, wt1b, st2w2, st2b, wt2w2, wt2b);

  gemm_mlp<<<dim3(32, 8), 256, 0, stream>>>(xbn, 1024, dwb, db, a_bf, 512, 1024, 0);
  gemm_mlp<<<dim3(32, 8), 256, 0, stream>>>(a_bf, 512, h1b, h1bias, t_bf, 512, 512, 1);
  gemm_mlp<<<dim3(32, 8), 256, 0, stream>>>(t_bf, 512, h2b, h2bias, h_bf, 512, 512, 0);
  gemm_zcat<<<dim3(147, 8), 256, 0, stream>>>(h_bf, wcat, Zcat, htcat, sums6, smallT);
  gemm_tail<<<dim3(284, 8), 256, 0, stream>>>(htcat, st1b, wt1b, st2b, wt2b,
                                              smallT, sums6);
  finals_kernel<<<1, 256, 0, stream>>>(Zcat, sums6, mom, rbf);
  final2<<<dim3(8, 460), 256, 0, stream>>>(rbf, qbf, EP, nsm, cv, smallT, out);
}

// Round 5
// 547.059 us; speedup vs baseline: 1.1641x; 1.1641x over previous
//
#include <hip/hip_runtime.h>
#include <stdint.h>

#define N_ROWS 512
#define D_IN 1024
#define ZCAT_COLS 2342
#define S_TOT 117660
#define S_PAD 117760
#define J_SLM 170000
#define J_WSD 107660

// Centers for bf16 residual storage of per-n constants (exact part goes via fp32 EP[s]).
#define C8f  (-18.49f)   // C3w
#define C17f (-18.95f)   // C3s
#define C18f (-6.91f)    // -lseHS
#define C19f (-14.51f)   // A1s
#define C20f (-15.76f)   // A2s
#define C21f (-6.91f)    // -lseHW
#define C22f (-14.51f)   // A1w
#define C23f (-15.76f)   // A2w

typedef __attribute__((ext_vector_type(8))) short short8;
typedef __attribute__((ext_vector_type(4))) float f32x4;

__device__ inline unsigned short f2bf(float f){
  unsigned int u = __float_as_uint(f);
  u += 0x7FFF + ((u >> 16) & 1);
  return (unsigned short)(u >> 16);
}

// ---------------- merged prep: bn partials | tail-3 moments | per-sense q build ----------------
// blocks [0,64): BN partial sums; [64,128): moments; [128,588): build_q. All independent.
__global__ __launch_bounds__(256) void prep_kernel(
  const float* __restrict__ x, float* __restrict__ colacc,
  const float* __restrict__ wS, const float* __restrict__ wW, float* __restrict__ mom,
  const int* __restrict__ sv_cols, const float* __restrict__ sv_vals,
  unsigned short* __restrict__ qbf, float* __restrict__ EP, int* __restrict__ nsm,
  uint2* __restrict__ cv)
{
  int b = blockIdx.x;
  __shared__ float lds[4][72];
  if (b < 64){
    // ---- BN partial sums ----
    int r0 = b * 8;
    int t = threadIdx.x;
    #pragma unroll
    for (int q = 0; q < 4; q++){
      int j = t + q * 256;
      float s1 = 0.f, s2 = 0.f;
      #pragma unroll
      for (int r = 0; r < 8; r++){
        float v = x[(size_t)(r0 + r) * D_IN + j];
        s1 += v; s2 += v * v;
      }
      atomicAdd(&colacc[j], s1);
      atomicAdd(&colacc[1024 + j], s2);
    }
    return;
  }
  if (b < 128){
    // ---- moments: 32 x-blocks per side ----
    int bb = b - 64;
    int side = bb >> 5;          // 0: SLM(wS), 1: WSD(wW)
    int xb = bb & 31;
    const float* w2 = side ? wW : wS;
    int J = side ? J_WSD : J_SLM;
    float* outp = mom + side * 72;
    float s1[8]; float m2[64];
    #pragma unroll
    for (int e = 0; e < 8; e++) s1[e] = 0.f;
    #pragma unroll
    for (int e = 0; e < 64; e++) m2[e] = 0.f;
    for (int r = xb * 256 + threadIdx.x; r < J; r += 32 * 256){
      const f32x4* p = (const f32x4*)(w2 + (size_t)r * 8);
      f32x4 wa = p[0], wb = p[1];
      float w[8] = {wa[0], wa[1], wa[2], wa[3], wb[0], wb[1], wb[2], wb[3]};
      #pragma unroll
      for (int a = 0; a < 8; a++){
        s1[a] += w[a];
        #pragma unroll
        for (int bq = 0; bq < 8; bq++) m2[a * 8 + bq] += w[a] * w[bq];
      }
    }
    int L = threadIdx.x & 63; int wave = threadIdx.x >> 6;
    #pragma unroll
    for (int e = 0; e < 72; e++){
      float v = (e < 8) ? s1[e] : m2[e - 8];
      #pragma unroll
      for (int d = 32; d > 0; d >>= 1) v += __shfl_down(v, d);
      if (L == 0) lds[wave][e] = v;
    }
    __syncthreads();
    int tt = threadIdx.x;
    if (tt < 72){
      float v = lds[0][tt] + lds[1][tt] + lds[2][tt] + lds[3][tt];
      atomicAdd(&outp[tt], v);
    }
    return;
  }
  // ---- build_q ----
  int s = (b - 128) * 256 + threadIdx.x;
  if (s >= S_PAD) return;
  unsigned short qr[32];
  #pragma unroll
  for (int e = 0; e < 32; e++) qr[e] = 0;
  uint2 pairs[10];
  #pragma unroll
  for (int e = 0; e < 10; e++){ pairs[e].x = 0; pairs[e].y = 0; }
  int idx = 0; float cw = 0.f, vh = 0.f, v1s = 0.f, v2s = 0.f;
  float w8[8];
  #pragma unroll
  for (int e = 0; e < 8; e++) w8[e] = 0.f;
  if (s < S_TOT){
    if (s < 10000){ pairs[0].x = (unsigned)(10000 + s); pairs[0].y = __float_as_uint(1.0f); idx = 1; }
    #pragma unroll
    for (int k = 0; k < 8; k++){
      int c = sv_cols[(size_t)s * 8 + k];
      float v = 0.1f * sv_vals[(size_t)s * 8 + k];
      if (c >= 10000){
        cw += v;
        const float* wr = wS + (size_t)(c - 10000) * 8;
        #pragma unroll
        for (int j = 0; j < 8; j++) w8[j] += v * wr[j];
      } else {
        pairs[idx].x = (unsigned)c; pairs[idx].y = __float_as_uint(v); idx++;
        if (c < 1000) vh += v; else if (c < 3000) v1s += v; else v2s += v;
      }
    }
    if (s >= 10000){
      const float* wrw = wW + (size_t)(s - 10000) * 8;
      #pragma unroll
      for (int j = 0; j < 8; j++) qr[j] = f2bf(wrw[j]);
      qr[8] = f2bf(1.0f);
    }
    #pragma unroll
    for (int j = 0; j < 8; j++) qr[9 + j] = f2bf(w8[j]);
    qr[17] = f2bf(cw); qr[18] = f2bf(vh); qr[19] = f2bf(v1s); qr[20] = f2bf(v2s);
    qr[21] = f2bf(s < 1000 ? 1.f : 0.f);
    qr[22] = f2bf((s >= 1000 && s < 3000) ? 1.f : 0.f);
    qr[23] = f2bf((s >= 3000 && s < 10000) ? 1.f : 0.f);
    float ep = (s >= 10000) ? C8f : (s < 1000 ? C21f : (s < 3000 ? C22f : C23f));
    ep += cw * C17f + vh * C18f + v1s * C19f + v2s * C20f;
    EP[s] = ep;
  } else {
    EP[s] = 0.f;
  }
  nsm[s] = idx;
  #pragma unroll
  for (int e = 0; e < 10; e++) cv[(size_t)s * 10 + e] = pairs[e];
  short8* qp = (short8*)(qbf + (size_t)s * 32);
  const short8* src = (const short8*)qr;
  qp[0] = src[0]; qp[1] = src[1]; qp[2] = src[2]; qp[3] = src[3];
}

// ---------------- fp32 -> bf16 conversion of everything (BN finalize inlined) ----------------
__global__ void convert_all(
  const float* __restrict__ x, const float* __restrict__ colacc,
  const float* __restrict__ gamma, const float* __restrict__ beta, unsigned short* __restrict__ xbn,
  const float* __restrict__ dw, unsigned short* __restrict__ dwb,
  const float* __restrict__ h1w, unsigned short* __restrict__ h1b,
  const float* __restrict__ h2w, unsigned short* __restrict__ h2b,
  const float* __restrict__ sh, const float* __restrict__ wh,
  const float* __restrict__ s11, const float* __restrict__ w11,
  const float* __restrict__ s21, const float* __restrict__ w21,
  const float* __restrict__ s31, const float* __restrict__ w31, unsigned short* __restrict__ wcat,
  const float* __restrict__ st1w2, unsigned short* __restrict__ st1b,
  const float* __restrict__ wt1w2, unsigned short* __restrict__ wt1b,
  const float* __restrict__ st2w2, unsigned short* __restrict__ st2b,
  const float* __restrict__ wt2w2, unsigned short* __restrict__ wt2b)
{
  size_t i = (size_t)blockIdx.x * 256 + threadIdx.x;
  const size_t o1 = 524288, o2 = o1 + 524288, o3 = o2 + 262144, o4 = o3 + 262144,
               o5 = o4 + 1199104, o6 = o5 + 256000, o7 = o6 + 256000, o8 = o7 + 224000,
               o9 = o8 + 224000;
  if (i < o1){
    int c = (int)(i & 1023);
    float mu = colacc[c] * (1.0f / 512.0f);
    float var = colacc[1024 + c] * (1.0f / 512.0f) - mu * mu;
    float sc = rsqrtf(var + 1e-5f) * gamma[c];
    float shv = beta[c] - mu * sc;
    xbn[i] = f2bf(x[i] * sc + shv);
  }
  else if (i < o2){ size_t l = i - o1; dwb[l] = f2bf(dw[l]); }
  else if (i < o3){ size_t l = i - o2; h1b[l] = f2bf(h1w[l]); }
  else if (i < o4){ size_t l = i - o3; h2b[l] = f2bf(h2w[l]); }
  else if (i < o5){
    size_t l = i - o4;
    float v;
    if (l < 513536) v = sh[l];
    else if (l < 1027072) v = wh[l - 513536];
    else if (l < 1092608) v = s11[l - 1027072];
    else if (l < 1158144) v = w11[l - 1092608];
    else if (l < 1174528) v = s21[l - 1158144];
    else if (l < 1190912) v = w21[l - 1174528];
    else if (l < 1195008) v = s31[l - 1190912];
    else v = w31[l - 1195008];
    wcat[l] = f2bf(v);
  }
  else if (i < o6){ size_t l = i - o5; st1b[l] = f2bf(st1w2[l]); }
  else if (i < o7){ size_t l = i - o6; wt1b[l] = f2bf(wt1w2[l]); }
  else if (i < o8){ size_t l = i - o7; st2b[l] = f2bf(st2w2[l]); }
  else if (i < o9){ size_t l = i - o8; wt2b[l] = f2bf(wt2w2[l]); }
}

// ---------------- MLP NT bf16 MFMA GEMM: C[m,n] = sum_k A[m,k]*B[n,k] -> bf16 ----------------
__global__ __launch_bounds__(256) void gemm_mlp(
  const unsigned short* __restrict__ A, int lda, const unsigned short* __restrict__ B,
  const float* __restrict__ bias, unsigned short* __restrict__ outB,
  int N, int K, int relu)
{
  int t = threadIdx.x; int wave = t >> 6; int L = t & 63; int quad = L >> 4; int l16 = L & 15;
  int mbase = blockIdx.y * 64 + wave * 16;
  int nb0 = blockIdx.x * 16;
  f32x4 acc = {0,0,0,0};
  int mrow = mbase + l16;
  const unsigned short* Ap = A + (size_t)mrow * lda + quad * 8;
  int nn = nb0 + l16;
  if (nn > N - 1) nn = N - 1;
  const unsigned short* Bp = B + (size_t)nn * K + quad * 8;
  for (int k0 = 0; k0 < K; k0 += 32){
    short8 a = *(const short8*)(Ap + k0);
    short8 b = *(const short8*)(Bp + k0);
    acc = __builtin_amdgcn_mfma_f32_16x16x32_bf16(a, b, acc, 0, 0, 0);
  }
  int n = nb0 + l16;
  if (n < N){
    float bv = bias ? bias[n] : 0.0f;
    #pragma unroll
    for (int r = 0; r < 4; r++){
      int m = mbase + quad * 4 + r;
      float v = acc[r] + bv;
      if (relu) v = fmaxf(v, 0.0f);
      outB[(size_t)m * N + n] = f2bf(v);
    }
  }
}

// ---------------- Zcat GEMM + head exp-sums + htcat + FUSED head transpose into smallT ----------
// Block tile = 16 cols x 64 m-rows. Head cols (c<1000 S-side, 1003<=c<2003 W-side) are
// transposed via LDS and written directly into smallT (kills the old build_smallT head pass).
// Zcat fp32 writes restricted to the 22 columns the finals kernel actually reads.
__global__ __launch_bounds__(256) void gemm_zcat(
  const unsigned short* __restrict__ A, const unsigned short* __restrict__ B,
  float* __restrict__ Zcat, unsigned short* __restrict__ htcat, float* __restrict__ sums6,
  float* __restrict__ smallT)
{
  const int N = ZCAT_COLS, K = 512;
  int t = threadIdx.x; int wave = t >> 6; int L = t & 63; int quad = L >> 4; int l16 = L & 15;
  int mbase = blockIdx.y * 64 + wave * 16;
  int nb0 = blockIdx.x * 16;
  f32x4 acc = {0,0,0,0};
  int mrow = mbase + l16;
  const unsigned short* Ap = A + (size_t)mrow * 512 + quad * 8;
  int nn = nb0 + l16;
  if (nn > N - 1) nn = N - 1;
  const unsigned short* Bp = B + (size_t)nn * K + quad * 8;
  for (int k0 = 0; k0 < K; k0 += 32){
    short8 a = *(const short8*)(Ap + k0);
    short8 b = *(const short8*)(Bp + k0);
    acc = __builtin_amdgcn_mfma_f32_16x16x32_bf16(a, b, acc, 0, 0, 0);
  }
  bool doEps = (nb0 < 2006);
  __shared__ float sacc[64][2];
  __shared__ float tile[16][65];
  if (doEps){
    for (int e = threadIdx.x; e < 128; e += 256) ((float*)sacc)[e] = 0.f;
    __syncthreads();
  }
  int c = nb0 + l16;
  #pragma unroll
  for (int r = 0; r < 4; r++){
    int m = mbase + quad * 4 + r;
    float v = acc[r];
    if (c < N){
      bool zkeep = (c >= 1000 && c < 1003) || (c >= 2003 && c < 2006) || (c >= 2326);
      if (zkeep) Zcat[(size_t)m * ZCAT_COLS + c] = v;
      if (c >= 2006) htcat[(size_t)m * 336 + (c - 2006)] = f2bf(v);
    }
    if (doEps){
      float e0 = (c < 1003) ? __expf(v) : 0.f;
      float e1 = (c >= 1003 && c < 2006) ? __expf(v) : 0.f;
      #pragma unroll
      for (int d = 8; d > 0; d >>= 1){ e0 += __shfl_xor(e0, d); e1 += __shfl_xor(e1, d); }
      if (l16 == 0){
        int mr = wave * 16 + quad * 4 + r;
        if (e0 != 0.f) atomicAdd(&sacc[mr][0], e0);
        if (e1 != 0.f) atomicAdd(&sacc[mr][1], e1);
      }
    }
  }
  bool doT = (nb0 < 2003);   // block-uniform
  if (doT){
    #pragma unroll
    for (int r = 0; r < 4; r++)
      tile[l16][wave * 16 + quad * 4 + r] = acc[r];
    __syncthreads();
    int tlo = t & 63, thi = t >> 6;
    int m0 = blockIdx.y * 64;
    #pragma unroll
    for (int p = 0; p < 4; p++){
      int cl = thi + p * 4;
      int cg = nb0 + cl;
      int row = -1;
      if (cg < 1000) row = cg;                              // S-side head
      else if (cg >= 1003 && cg < 2003) row = 10000 + (cg - 1003);  // W-side head
      if (row >= 0) smallT[(size_t)row * 512 + m0 + tlo] = tile[cl][tlo];
    }
  }
  if (doEps){
    __syncthreads();
    int tt = threadIdx.x;
    if (tt < 128){
      int mr = tt >> 1;
      float v = sacc[mr][tt & 1];
      if (v != 0.f) atomicAdd(&sums6[(blockIdx.y * 64 + mr) * 8 + (tt & 1)], v);
    }
  }
}

// ---------------- merged tail GEMMs + exp-sums + FUSED transposed write into smallT ----------------
// Flattened grid: bx in [0,32) zi=0; [32,64) zi=1; [64,174) zi=2; [174,284) zi=3 (no dead blocks).
// smallT row bases: z1S->1000, z1W->11000, z2S->3000, z2W->13000.
__global__ __launch_bounds__(256) void gemm_tail(
  const unsigned short* __restrict__ htcat,
  const unsigned short* __restrict__ b0, const unsigned short* __restrict__ b1,
  const unsigned short* __restrict__ b2, const unsigned short* __restrict__ b3,
  float* __restrict__ smallT, float* __restrict__ sums6)
{
  int bx = blockIdx.x;
  int zi, nbx;
  if (bx < 32){ zi = 0; nbx = bx; }
  else if (bx < 64){ zi = 1; nbx = bx - 32; }
  else if (bx < 174){ zi = 2; nbx = bx - 64; }
  else { zi = 3; nbx = bx - 174; }
  int N = (zi < 2) ? 2000 : 7000;
  int K = (zi < 2) ? 128 : 32;
  int aoff = (zi == 0) ? 0 : (zi == 1) ? 128 : (zi == 2) ? 256 : 288;
  int rowbase = (zi == 0) ? 1000 : (zi == 1) ? 11000 : (zi == 2) ? 3000 : 13000;
  const unsigned short* B = (zi == 0) ? b0 : (zi == 1) ? b1 : (zi == 2) ? b2 : b3;
  int nb0 = nbx * 64;
  int t = threadIdx.x; int wave = t >> 6; int L = t & 63; int quad = L >> 4; int l16 = L & 15;
  int mbase = blockIdx.y * 64 + wave * 16;
  f32x4 acc[4] = {{0,0,0,0},{0,0,0,0},{0,0,0,0},{0,0,0,0}};
  int mrow = mbase + l16;
  const unsigned short* Ap = htcat + (size_t)mrow * 336 + aoff + quad * 8;
  const unsigned short* Bp[4];
  #pragma unroll
  for (int j = 0; j < 4; j++){
    int n = nb0 + j * 16 + l16;
    if (n > N - 1) n = N - 1;
    Bp[j] = B + (size_t)n * K + quad * 8;
  }
  for (int k0 = 0; k0 < K; k0 += 32){
    short8 a = *(const short8*)(Ap + k0);
    #pragma unroll
    for (int j = 0; j < 4; j++){
      short8 b = *(const short8*)(Bp[j] + k0);
      acc[j] = __builtin_amdgcn_mfma_f32_16x16x32_bf16(a, b, acc[j], 0, 0, 0);
    }
  }
  __shared__ float sacc[64];
  __shared__ float tile[64][65];
  for (int e = threadIdx.x; e < 64; e += 256) sacc[e] = 0.f;
  __syncthreads();
  #pragma unroll
  for (int j = 0; j < 4; j++){
    int n = nb0 + j * 16 + l16;
    #pragma unroll
    for (int r = 0; r < 4; r++){
      int mloc = wave * 16 + quad * 4 + r;
      float v = acc[j][r];
      tile[j * 16 + l16][mloc] = v;
      float e = (n < N) ? __expf(v) : 0.f;
      #pragma unroll
      for (int d = 8; d > 0; d >>= 1) e += __shfl_xor(e, d);
      if (l16 == 0) atomicAdd(&sacc[mloc], e);
    }
  }
  __syncthreads();
  // transposed write-out: 64 c-rows x 64 m-cols, coalesced along m
  int tlo = t & 63, thi = t >> 6;
  int m0 = blockIdx.y * 64 + tlo;
  #pragma unroll
  for (int p = 0; p < 16; p++){
    int cl = thi + p * 4;
    int cg = nb0 + cl;
    if (cg < N) smallT[(size_t)(rowbase + cg) * 512 + m0] = tile[cl][tlo];
  }
  if (threadIdx.x < 64){
    float v = sacc[threadIdx.x];
    atomicAdd(&sums6[(blockIdx.y * 64 + threadIdx.x) * 8 + 2 + zi], v);
  }
}

// ---------------- per-n finals -> rbf (single block) ----------------
__global__ __launch_bounds__(256) void finals_kernel(const float* __restrict__ Zcat,
                                                     const float* __restrict__ sums6,
                                                     const float* __restrict__ mom,
                                                     unsigned short* __restrict__ rbf){
  for (int n = threadIdx.x; n < 512; n += 256){
    const float* zrow = Zcat + (size_t)n * ZCAT_COLS;
    float lseHS = __logf(sums6[n * 8 + 0]), lseHW = __logf(sums6[n * 8 + 1]);
    float lse1S = __logf(sums6[n * 8 + 2]), lse1W = __logf(sums6[n * 8 + 3]);
    float lse2S = __logf(sums6[n * 8 + 4]), lse2W = __logf(sums6[n * 8 + 5]);
    float uS[8], uW[8];
    #pragma unroll
    for (int j = 0; j < 8; j++){ uS[j] = zrow[2326 + j]; uW[j] = zrow[2334 + j]; }
    const float* mS = mom; const float* mW = mom + 72;
    float d1 = 0.f, d2 = 0.f, e1 = 0.f, e2 = 0.f;
    #pragma unroll
    for (int a = 0; a < 8; a++){
      d1 += uS[a] * mS[a]; e1 += uW[a] * mW[a];
      #pragma unroll
      for (int b = 0; b < 8; b++){
        d2 += uS[a] * uS[b] * mS[8 + a * 8 + b];
        e2 += uW[a] * uW[b] * mW[8 + a * 8 + b];
      }
    }
    float lse3S = __logf((float)J_SLM + d1 + 0.5f * d2);
    float lse3W = __logf((float)J_WSD + e1 + 0.5f * e2);
    float C3w = (zrow[2005] - lseHW) - lse3W;
    float C3s = (zrow[1002] - lseHS) - lse3S;
    float A1s = zrow[1000] - lseHS - lse1S;
    float A2s = zrow[1001] - lseHS - lse2S;
    float A1w = zrow[2003] - lseHW - lse1W;
    float A2w = zrow[2004] - lseHW - lse2W;
    unsigned short* rr = rbf + n * 32;
    #pragma unroll
    for (int j = 0; j < 8; j++){ rr[j] = f2bf(uW[j]); rr[9 + j] = f2bf(uS[j]); }
    rr[8]  = f2bf(C3w - C8f);
    rr[17] = f2bf(C3s - C17f);
    rr[18] = f2bf(-lseHS - C18f);
    rr[19] = f2bf(A1s - C19f);
    rr[20] = f2bf(A2s - C20f);
    rr[21] = f2bf(-lseHW - C21f);
    rr[22] = f2bf(A1w - C22f);
    rr[23] = f2bf(A2w - C23f);
    #pragma unroll
    for (int j = 24; j < 32; j++) rr[j] = 0;
  }
}

// ---------------- the big output kernel ----------------
// Grid (8,460): blockIdx.x (fastest-varying) carries the n-split (prologue re-reads L3-hot).
// out stores are PLAIN (through L2): R4 measured nt-stores lose L2 write-combining —
// WRITE_SIZE 294->329MB and write BW collapsed (final2 195->245us) despite FETCH −52MB.
__global__ __launch_bounds__(256, 4) void final2(
  const unsigned short* __restrict__ rbf, const unsigned short* __restrict__ qbf,
  const float* __restrict__ EP, const int* __restrict__ nsm,
  const uint2* __restrict__ cv, const float* __restrict__ smallT,
  float* __restrict__ out)
{
  int t = threadIdx.x; int wave = t >> 6; int L = t & 63; int quad = L >> 4; int l16 = L & 15;
  int sbase = blockIdx.y * 256 + wave * 64;
  int nbase = blockIdx.x * 64;
  short8 bfrag[4]; float ep[4]; int cnt[4]; int kmax[4];
  int ccol[4][3]; float cval[4][3];
  #pragma unroll
  for (int j = 0; j < 4; j++){
    int s = sbase + j * 16 + l16;
    bfrag[j] = *(const short8*)(qbf + (size_t)s * 32 + quad * 8);
    ep[j] = EP[s]; cnt[j] = nsm[s];
    #pragma unroll
    for (int k = 0; k < 3; k++){
      uint2 e = cv[(size_t)s * 10 + k];
      ccol[j][k] = (int)e.x; cval[j][k] = __uint_as_float(e.y);
    }
    int kw = cnt[j];
    #pragma unroll
    for (int d = 32; d > 0; d >>= 1){ int o = __shfl_xor(kw, d); kw = (o > kw) ? o : kw; }
    kmax[j] = __builtin_amdgcn_readfirstlane(kw);
  }
  for (int i = 0; i < 4; i++){
    int n0 = nbase + i * 16;
    short8 afrag = *(const short8*)(rbf + (size_t)(n0 + l16) * 32 + quad * 8);
    int nq = n0 + quad * 4;
    #pragma unroll
    for (int j = 0; j < 4; j++){
      f32x4 acc = {0.f, 0.f, 0.f, 0.f};
      acc = __builtin_amdgcn_mfma_f32_16x16x32_bf16(afrag, bfrag[j], acc, 0, 0, 0);
      f32x4 res = acc + ep[j];
      #pragma unroll
      for (int k = 0; k < 3; k++){
        if (k < kmax[j]){                 // wave-uniform skip
          if (k < cnt[j]){                // per-lane mask
            const f32x4* p = (const f32x4*)(smallT + ((size_t)ccol[j][k] << 9) + nq);
            res += cval[j][k] * (*p);
          }
        }
      }
      if (kmax[j] >= 4){                  // rare overflow path (P ~ 1%)
        int s = sbase + j * 16 + l16;
        for (int k = 3; k < 9; k++){
          if (k < cnt[j]){
            uint2 e = cv[(size_t)s * 10 + k];
            const f32x4* p = (const f32x4*)(smallT + ((size_t)e.x << 9) + nq);
            res += __uint_as_float(e.y) * (*p);
          }
        }
      }
      int sj = sbase + j * 16 + l16;
      if (sj < S_TOT){
        #pragma unroll
        for (int r = 0; r < 4; r++)
          out[(size_t)(nq + r) * S_TOT + sj] = res[r];
      }
    }
  }
}

extern "C" void kernel_launch(void* const* d_in, const int* in_sizes, int n_in,
                              void* d_out, int out_size, void* d_ws, size_t ws_size,
                              hipStream_t stream)
{
  const float* x      = (const float*)d_in[0];
  const float* gamma  = (const float*)d_in[1];
  const float* beta   = (const float*)d_in[2];
  const float* dw     = (const float*)d_in[3];
  const float* db     = (const float*)d_in[4];
  const float* h1w    = (const float*)d_in[5];
  const float* h1bias = (const float*)d_in[6];
  const float* h2w    = (const float*)d_in[7];
  const float* h2bias = (const float*)d_in[8];
  const float* whead  = (const float*)d_in[9];
  const float* wt1w1  = (const float*)d_in[10];
  const float* wt1w2  = (const float*)d_in[11];
  const float* wt2w1  = (const float*)d_in[12];
  const float* wt2w2  = (const float*)d_in[13];
  const float* wt3w1  = (const float*)d_in[14];
  const float* wt3w2  = (const float*)d_in[15];
  const float* shead  = (const float*)d_in[16];
  const float* st1w1  = (const float*)d_in[17];
  const float* st1w2  = (const float*)d_in[18];
  const float* st2w1  = (const float*)d_in[19];
  const float* st2w2  = (const float*)d_in[20];
  const float* st3w1  = (const float*)d_in[21];
  const float* st3w2  = (const float*)d_in[22];
  const float* svv    = (const float*)d_in[23];
  const int*   svc    = (const int*)d_in[24];
  float* out = (float*)d_out;

  char* wsb = (char*)d_ws; size_t off = 0;
  auto alloc = [&](size_t bytes) -> void* {
    void* p = wsb + off;
    off = (off + bytes + 255) & ~(size_t)255;
    return p;
  };
  // zero-init region (one memset): colacc | mom | sums6
  float* colacc = (float*)alloc(2048 * 4);
  float* mom    = (float*)alloc(2 * 72 * 4);
  float* sums6  = (float*)alloc(512 * 8 * 4);
  size_t zero_bytes = ((char*)sums6 - (char*)colacc) + 512 * 8 * 4;

  unsigned short* xbn   = (unsigned short*)alloc((size_t)512 * 1024 * 2);
  unsigned short* dwb   = (unsigned short*)alloc((size_t)512 * 1024 * 2);
  unsigned short* h1b   = (unsigned short*)alloc((size_t)512 * 512 * 2);
  unsigned short* h2b   = (unsigned short*)alloc((size_t)512 * 512 * 2);
  unsigned short* wcat  = (unsigned short*)alloc((size_t)ZCAT_COLS * 512 * 2);
  unsigned short* st1b  = (unsigned short*)alloc((size_t)2000 * 128 * 2);
  unsigned short* wt1b  = (unsigned short*)alloc((size_t)2000 * 128 * 2);
  unsigned short* st2b  = (unsigned short*)alloc((size_t)7000 * 32 * 2);
  unsigned short* wt2b  = (unsigned short*)alloc((size_t)7000 * 32 * 2);
  unsigned short* a_bf  = (unsigned short*)alloc((size_t)512 * 512 * 2);
  unsigned short* t_bf  = (unsigned short*)alloc((size_t)512 * 512 * 2);
  unsigned short* h_bf  = (unsigned short*)alloc((size_t)512 * 512 * 2);
  unsigned short* htcat = (unsigned short*)alloc((size_t)512 * 336 * 2);
  float* Zcat  = (float*)alloc((size_t)512 * ZCAT_COLS * 4);
  unsigned short* rbf = (unsigned short*)alloc((size_t)512 * 32 * 2);
  float* smallT = (float*)alloc((size_t)20000 * 512 * 4);
  unsigned short* qbf = (unsigned short*)alloc((size_t)S_PAD * 32 * 2);
  float* EP  = (float*)alloc((size_t)S_PAD * 4);
  int*   nsm = (int*)alloc((size_t)S_PAD * 4);
  uint2* cv  = (uint2*)alloc((size_t)S_PAD * 10 * 8);

  (void)in_sizes; (void)n_in; (void)out_size; (void)ws_size;

  hipMemsetAsync(colacc, 0, zero_bytes, stream);
  prep_kernel<<<588, 256, 0, stream>>>(x, colacc, st3w2, wt3w2, mom,
                                       svc, svv, qbf, EP, nsm, cv);
  convert_all<<<14578, 256, 0, stream>>>(
      x, colacc, gamma, beta, xbn, dw, dwb, h1w, h1b, h2w, h2b,
      shead, whead, st1w1, wt1w1, st2w1, wt2w1, st3w1, wt3w1, wcat,
      st1w2, st1b, wt1w2, wt1b, st2w2, st2b, wt2w2, wt2b);

  gemm_mlp<<<dim3(32, 8), 256, 0, stream>>>(xbn, 1024, dwb, db, a_bf, 512, 1024, 0);
  gemm_mlp<<<dim3(32, 8), 256, 0, stream>>>(a_bf, 512, h1b, h1bias, t_bf, 512, 512, 1);
  gemm_mlp<<<dim3(32, 8), 256, 0, stream>>>(t_bf, 512, h2b, h2bias, h_bf, 512, 512, 0);
  gemm_zcat<<<dim3(147, 8), 256, 0, stream>>>(h_bf, wcat, Zcat, htcat, sums6, smallT);
  gemm_tail<<<dim3(284, 8), 256, 0, stream>>>(htcat, st1b, wt1b, st2b, wt2b,
                                              smallT, sums6);
  finals_kernel<<<1, 256, 0, stream>>>(Zcat, sums6, mom, rbf);
  final2<<<dim3(8, 460), 256, 0, stream>>>(rbf, qbf, EP, nsm, cv, smallT, out);
}

// Round 6
// 529.884 us; speedup vs baseline: 1.2018x; 1.0324x over previous
//
#include <hip/hip_runtime.h>
#include <stdint.h>

#define N_ROWS 512
#define D_IN 1024
#define ZCAT_COLS 2342
#define S_TOT 117660
#define S_PAD 117760
#define J_SLM 170000
#define J_WSD 107660

// Centers for bf16 residual storage of per-n constants (exact part goes via fp32 EP[s]).
#define C8f  (-18.49f)   // C3w
#define C17f (-18.95f)   // C3s
#define C18f (-6.91f)    // -lseHS
#define C19f (-14.51f)   // A1s
#define C20f (-15.76f)   // A2s
#define C21f (-6.91f)    // -lseHW
#define C22f (-14.51f)   // A1w
#define C23f (-15.76f)   // A2w

typedef __attribute__((ext_vector_type(8))) short short8;
typedef __attribute__((ext_vector_type(4))) float f32x4;
typedef __attribute__((ext_vector_type(4))) unsigned short ushort4v;

__device__ inline unsigned short f2bf(float f){
  unsigned int u = __float_as_uint(f);
  u += 0x7FFF + ((u >> 16) & 1);
  return (unsigned short)(u >> 16);
}
__device__ inline float bf2f(unsigned short u){
  return __uint_as_float((unsigned int)u << 16);
}

// ---------------- merged prep: bn partials | tail-3 moments | per-sense q build ----------------
// blocks [0,64): BN partial sums; [64,128): moments; [128,588): build_q. All independent.
__global__ __launch_bounds__(256) void prep_kernel(
  const float* __restrict__ x, float* __restrict__ colacc,
  const float* __restrict__ wS, const float* __restrict__ wW, float* __restrict__ mom,
  const int* __restrict__ sv_cols, const float* __restrict__ sv_vals,
  unsigned short* __restrict__ qbf, float* __restrict__ EP, int* __restrict__ nsm,
  uint2* __restrict__ cv)
{
  int b = blockIdx.x;
  __shared__ float lds[4][72];
  if (b < 64){
    // ---- BN partial sums ----
    int r0 = b * 8;
    int t = threadIdx.x;
    #pragma unroll
    for (int q = 0; q < 4; q++){
      int j = t + q * 256;
      float s1 = 0.f, s2 = 0.f;
      #pragma unroll
      for (int r = 0; r < 8; r++){
        float v = x[(size_t)(r0 + r) * D_IN + j];
        s1 += v; s2 += v * v;
      }
      atomicAdd(&colacc[j], s1);
      atomicAdd(&colacc[1024 + j], s2);
    }
    return;
  }
  if (b < 128){
    // ---- moments: 32 x-blocks per side ----
    int bb = b - 64;
    int side = bb >> 5;          // 0: SLM(wS), 1: WSD(wW)
    int xb = bb & 31;
    const float* w2 = side ? wW : wS;
    int J = side ? J_WSD : J_SLM;
    float* outp = mom + side * 72;
    float s1[8]; float m2[64];
    #pragma unroll
    for (int e = 0; e < 8; e++) s1[e] = 0.f;
    #pragma unroll
    for (int e = 0; e < 64; e++) m2[e] = 0.f;
    for (int r = xb * 256 + threadIdx.x; r < J; r += 32 * 256){
      const f32x4* p = (const f32x4*)(w2 + (size_t)r * 8);
      f32x4 wa = p[0], wb = p[1];
      float w[8] = {wa[0], wa[1], wa[2], wa[3], wb[0], wb[1], wb[2], wb[3]};
      #pragma unroll
      for (int a = 0; a < 8; a++){
        s1[a] += w[a];
        #pragma unroll
        for (int bq = 0; bq < 8; bq++) m2[a * 8 + bq] += w[a] * w[bq];
      }
    }
    int L = threadIdx.x & 63; int wave = threadIdx.x >> 6;
    #pragma unroll
    for (int e = 0; e < 72; e++){
      float v = (e < 8) ? s1[e] : m2[e - 8];
      #pragma unroll
      for (int d = 32; d > 0; d >>= 1) v += __shfl_down(v, d);
      if (L == 0) lds[wave][e] = v;
    }
    __syncthreads();
    int tt = threadIdx.x;
    if (tt < 72){
      float v = lds[0][tt] + lds[1][tt] + lds[2][tt] + lds[3][tt];
      atomicAdd(&outp[tt], v);
    }
    return;
  }
  // ---- build_q ----
  int s = (b - 128) * 256 + threadIdx.x;
  if (s >= S_PAD) return;
  unsigned short qr[32];
  #pragma unroll
  for (int e = 0; e < 32; e++) qr[e] = 0;
  uint2 pairs[10];
  #pragma unroll
  for (int e = 0; e < 10; e++){ pairs[e].x = 0; pairs[e].y = 0; }
  int idx = 0; float cw = 0.f, vh = 0.f, v1s = 0.f, v2s = 0.f;
  float w8[8];
  #pragma unroll
  for (int e = 0; e < 8; e++) w8[e] = 0.f;
  if (s < S_TOT){
    if (s < 10000){ pairs[0].x = (unsigned)(10000 + s); pairs[0].y = __float_as_uint(1.0f); idx = 1; }
    #pragma unroll
    for (int k = 0; k < 8; k++){
      int c = sv_cols[(size_t)s * 8 + k];
      float v = 0.1f * sv_vals[(size_t)s * 8 + k];
      if (c >= 10000){
        cw += v;
        const float* wr = wS + (size_t)(c - 10000) * 8;
        #pragma unroll
        for (int j = 0; j < 8; j++) w8[j] += v * wr[j];
      } else {
        pairs[idx].x = (unsigned)c; pairs[idx].y = __float_as_uint(v); idx++;
        if (c < 1000) vh += v; else if (c < 3000) v1s += v; else v2s += v;
      }
    }
    if (s >= 10000){
      const float* wrw = wW + (size_t)(s - 10000) * 8;
      #pragma unroll
      for (int j = 0; j < 8; j++) qr[j] = f2bf(wrw[j]);
      qr[8] = f2bf(1.0f);
    }
    #pragma unroll
    for (int j = 0; j < 8; j++) qr[9 + j] = f2bf(w8[j]);
    qr[17] = f2bf(cw); qr[18] = f2bf(vh); qr[19] = f2bf(v1s); qr[20] = f2bf(v2s);
    qr[21] = f2bf(s < 1000 ? 1.f : 0.f);
    qr[22] = f2bf((s >= 1000 && s < 3000) ? 1.f : 0.f);
    qr[23] = f2bf((s >= 3000 && s < 10000) ? 1.f : 0.f);
    float ep = (s >= 10000) ? C8f : (s < 1000 ? C21f : (s < 3000 ? C22f : C23f));
    ep += cw * C17f + vh * C18f + v1s * C19f + v2s * C20f;
    EP[s] = ep;
  } else {
    EP[s] = 0.f;
  }
  nsm[s] = idx;
  #pragma unroll
  for (int e = 0; e < 10; e++) cv[(size_t)s * 10 + e] = pairs[e];
  short8* qp = (short8*)(qbf + (size_t)s * 32);
  const short8* src = (const short8*)qr;
  qp[0] = src[0]; qp[1] = src[1]; qp[2] = src[2]; qp[3] = src[3];
}

// ---------------- fp32 -> bf16 conversion of everything (BN finalize inlined) ----------------
__global__ void convert_all(
  const float* __restrict__ x, const float* __restrict__ colacc,
  const float* __restrict__ gamma, const float* __restrict__ beta, unsigned short* __restrict__ xbn,
  const float* __restrict__ dw, unsigned short* __restrict__ dwb,
  const float* __restrict__ h1w, unsigned short* __restrict__ h1b,
  const float* __restrict__ h2w, unsigned short* __restrict__ h2b,
  const float* __restrict__ sh, const float* __restrict__ wh,
  const float* __restrict__ s11, const float* __restrict__ w11,
  const float* __restrict__ s21, const float* __restrict__ w21,
  const float* __restrict__ s31, const float* __restrict__ w31, unsigned short* __restrict__ wcat,
  const float* __restrict__ st1w2, unsigned short* __restrict__ st1b,
  const float* __restrict__ wt1w2, unsigned short* __restrict__ wt1b,
  const float* __restrict__ st2w2, unsigned short* __restrict__ st2b,
  const float* __restrict__ wt2w2, unsigned short* __restrict__ wt2b)
{
  size_t i = (size_t)blockIdx.x * 256 + threadIdx.x;
  const size_t o1 = 524288, o2 = o1 + 524288, o3 = o2 + 262144, o4 = o3 + 262144,
               o5 = o4 + 1199104, o6 = o5 + 256000, o7 = o6 + 256000, o8 = o7 + 224000,
               o9 = o8 + 224000;
  if (i < o1){
    int c = (int)(i & 1023);
    float mu = colacc[c] * (1.0f / 512.0f);
    float var = colacc[1024 + c] * (1.0f / 512.0f) - mu * mu;
    float sc = rsqrtf(var + 1e-5f) * gamma[c];
    float shv = beta[c] - mu * sc;
    xbn[i] = f2bf(x[i] * sc + shv);
  }
  else if (i < o2){ size_t l = i - o1; dwb[l] = f2bf(dw[l]); }
  else if (i < o3){ size_t l = i - o2; h1b[l] = f2bf(h1w[l]); }
  else if (i < o4){ size_t l = i - o3; h2b[l] = f2bf(h2w[l]); }
  else if (i < o5){
    size_t l = i - o4;
    float v;
    if (l < 513536) v = sh[l];
    else if (l < 1027072) v = wh[l - 513536];
    else if (l < 1092608) v = s11[l - 1027072];
    else if (l < 1158144) v = w11[l - 1092608];
    else if (l < 1174528) v = s21[l - 1158144];
    else if (l < 1190912) v = w21[l - 1174528];
    else if (l < 1195008) v = s31[l - 1190912];
    else v = w31[l - 1195008];
    wcat[l] = f2bf(v);
  }
  else if (i < o6){ size_t l = i - o5; st1b[l] = f2bf(st1w2[l]); }
  else if (i < o7){ size_t l = i - o6; wt1b[l] = f2bf(wt1w2[l]); }
  else if (i < o8){ size_t l = i - o7; st2b[l] = f2bf(st2w2[l]); }
  else if (i < o9){ size_t l = i - o8; wt2b[l] = f2bf(wt2w2[l]); }
}

// ---------------- MLP NT bf16 MFMA GEMM: C[m,n] = sum_k A[m,k]*B[n,k] -> bf16 ----------------
__global__ __launch_bounds__(256) void gemm_mlp(
  const unsigned short* __restrict__ A, int lda, const unsigned short* __restrict__ B,
  const float* __restrict__ bias, unsigned short* __restrict__ outB,
  int N, int K, int relu)
{
  int t = threadIdx.x; int wave = t >> 6; int L = t & 63; int quad = L >> 4; int l16 = L & 15;
  int mbase = blockIdx.y * 64 + wave * 16;
  int nb0 = blockIdx.x * 16;
  f32x4 acc = {0,0,0,0};
  int mrow = mbase + l16;
  const unsigned short* Ap = A + (size_t)mrow * lda + quad * 8;
  int nn = nb0 + l16;
  if (nn > N - 1) nn = N - 1;
  const unsigned short* Bp = B + (size_t)nn * K + quad * 8;
  for (int k0 = 0; k0 < K; k0 += 32){
    short8 a = *(const short8*)(Ap + k0);
    short8 b = *(const short8*)(Bp + k0);
    acc = __builtin_amdgcn_mfma_f32_16x16x32_bf16(a, b, acc, 0, 0, 0);
  }
  int n = nb0 + l16;
  if (n < N){
    float bv = bias ? bias[n] : 0.0f;
    #pragma unroll
    for (int r = 0; r < 4; r++){
      int m = mbase + quad * 4 + r;
      float v = acc[r] + bv;
      if (relu) v = fmaxf(v, 0.0f);
      outB[(size_t)m * N + n] = f2bf(v);
    }
  }
}

// ---------------- Zcat GEMM + head exp-sums + htcat + FUSED head transpose into smallT ----------
// smallT is now bf16 (raw logits |v|<~2, bf16 err ~0.004 << absmax 0.125).
__global__ __launch_bounds__(256) void gemm_zcat(
  const unsigned short* __restrict__ A, const unsigned short* __restrict__ B,
  float* __restrict__ Zcat, unsigned short* __restrict__ htcat, float* __restrict__ sums6,
  unsigned short* __restrict__ smallT)
{
  const int N = ZCAT_COLS, K = 512;
  int t = threadIdx.x; int wave = t >> 6; int L = t & 63; int quad = L >> 4; int l16 = L & 15;
  int mbase = blockIdx.y * 64 + wave * 16;
  int nb0 = blockIdx.x * 16;
  f32x4 acc = {0,0,0,0};
  int mrow = mbase + l16;
  const unsigned short* Ap = A + (size_t)mrow * 512 + quad * 8;
  int nn = nb0 + l16;
  if (nn > N - 1) nn = N - 1;
  const unsigned short* Bp = B + (size_t)nn * K + quad * 8;
  for (int k0 = 0; k0 < K; k0 += 32){
    short8 a = *(const short8*)(Ap + k0);
    short8 b = *(const short8*)(Bp + k0);
    acc = __builtin_amdgcn_mfma_f32_16x16x32_bf16(a, b, acc, 0, 0, 0);
  }
  bool doEps = (nb0 < 2006);
  __shared__ float sacc[64][2];
  __shared__ float tile[16][65];
  if (doEps){
    for (int e = threadIdx.x; e < 128; e += 256) ((float*)sacc)[e] = 0.f;
    __syncthreads();
  }
  int c = nb0 + l16;
  #pragma unroll
  for (int r = 0; r < 4; r++){
    int m = mbase + quad * 4 + r;
    float v = acc[r];
    if (c < N){
      bool zkeep = (c >= 1000 && c < 1003) || (c >= 2003 && c < 2006) || (c >= 2326);
      if (zkeep) Zcat[(size_t)m * ZCAT_COLS + c] = v;
      if (c >= 2006) htcat[(size_t)m * 336 + (c - 2006)] = f2bf(v);
    }
    if (doEps){
      float e0 = (c < 1003) ? __expf(v) : 0.f;
      float e1 = (c >= 1003 && c < 2006) ? __expf(v) : 0.f;
      #pragma unroll
      for (int d = 8; d > 0; d >>= 1){ e0 += __shfl_xor(e0, d); e1 += __shfl_xor(e1, d); }
      if (l16 == 0){
        int mr = wave * 16 + quad * 4 + r;
        if (e0 != 0.f) atomicAdd(&sacc[mr][0], e0);
        if (e1 != 0.f) atomicAdd(&sacc[mr][1], e1);
      }
    }
  }
  bool doT = (nb0 < 2003);   // block-uniform
  if (doT){
    #pragma unroll
    for (int r = 0; r < 4; r++)
      tile[l16][wave * 16 + quad * 4 + r] = acc[r];
    __syncthreads();
    int tlo = t & 63, thi = t >> 6;
    int m0 = blockIdx.y * 64;
    #pragma unroll
    for (int p = 0; p < 4; p++){
      int cl = thi + p * 4;
      int cg = nb0 + cl;
      int row = -1;
      if (cg < 1000) row = cg;                              // S-side head
      else if (cg >= 1003 && cg < 2003) row = 10000 + (cg - 1003);  // W-side head
      if (row >= 0) smallT[(size_t)row * 512 + m0 + tlo] = f2bf(tile[cl][tlo]);
    }
  }
  if (doEps){
    __syncthreads();
    int tt = threadIdx.x;
    if (tt < 128){
      int mr = tt >> 1;
      float v = sacc[mr][tt & 1];
      if (v != 0.f) atomicAdd(&sums6[(blockIdx.y * 64 + mr) * 8 + (tt & 1)], v);
    }
  }
}

// ---------------- merged tail GEMMs + exp-sums + FUSED transposed bf16 write into smallT ----------
// Flattened grid: bx in [0,32) zi=0; [32,64) zi=1; [64,174) zi=2; [174,284) zi=3 (no dead blocks).
// smallT row bases: z1S->1000, z1W->11000, z2S->3000, z2W->13000.
__global__ __launch_bounds__(256) void gemm_tail(
  const unsigned short* __restrict__ htcat,
  const unsigned short* __restrict__ b0, const unsigned short* __restrict__ b1,
  const unsigned short* __restrict__ b2, const unsigned short* __restrict__ b3,
  unsigned short* __restrict__ smallT, float* __restrict__ sums6)
{
  int bx = blockIdx.x;
  int zi, nbx;
  if (bx < 32){ zi = 0; nbx = bx; }
  else if (bx < 64){ zi = 1; nbx = bx - 32; }
  else if (bx < 174){ zi = 2; nbx = bx - 64; }
  else { zi = 3; nbx = bx - 174; }
  int N = (zi < 2) ? 2000 : 7000;
  int K = (zi < 2) ? 128 : 32;
  int aoff = (zi == 0) ? 0 : (zi == 1) ? 128 : (zi == 2) ? 256 : 288;
  int rowbase = (zi == 0) ? 1000 : (zi == 1) ? 11000 : (zi == 2) ? 3000 : 13000;
  const unsigned short* B = (zi == 0) ? b0 : (zi == 1) ? b1 : (zi == 2) ? b2 : b3;
  int nb0 = nbx * 64;
  int t = threadIdx.x; int wave = t >> 6; int L = t & 63; int quad = L >> 4; int l16 = L & 15;
  int mbase = blockIdx.y * 64 + wave * 16;
  f32x4 acc[4] = {{0,0,0,0},{0,0,0,0},{0,0,0,0},{0,0,0,0}};
  int mrow = mbase + l16;
  const unsigned short* Ap = htcat + (size_t)mrow * 336 + aoff + quad * 8;
  const unsigned short* Bp[4];
  #pragma unroll
  for (int j = 0; j < 4; j++){
    int n = nb0 + j * 16 + l16;
    if (n > N - 1) n = N - 1;
    Bp[j] = B + (size_t)n * K + quad * 8;
  }
  for (int k0 = 0; k0 < K; k0 += 32){
    short8 a = *(const short8*)(Ap + k0);
    #pragma unroll
    for (int j = 0; j < 4; j++){
      short8 b = *(const short8*)(Bp[j] + k0);
      acc[j] = __builtin_amdgcn_mfma_f32_16x16x32_bf16(a, b, acc[j], 0, 0, 0);
    }
  }
  __shared__ float sacc[64];
  __shared__ float tile[64][65];
  for (int e = threadIdx.x; e < 64; e += 256) sacc[e] = 0.f;
  __syncthreads();
  #pragma unroll
  for (int j = 0; j < 4; j++){
    int n = nb0 + j * 16 + l16;
    #pragma unroll
    for (int r = 0; r < 4; r++){
      int mloc = wave * 16 + quad * 4 + r;
      float v = acc[j][r];
      tile[j * 16 + l16][mloc] = v;
      float e = (n < N) ? __expf(v) : 0.f;
      #pragma unroll
      for (int d = 8; d > 0; d >>= 1) e += __shfl_xor(e, d);
      if (l16 == 0) atomicAdd(&sacc[mloc], e);
    }
  }
  __syncthreads();
  // transposed write-out: 64 c-rows x 64 m-cols, coalesced along m (bf16)
  int tlo = t & 63, thi = t >> 6;
  int m0 = blockIdx.y * 64 + tlo;
  #pragma unroll
  for (int p = 0; p < 16; p++){
    int cl = thi + p * 4;
    int cg = nb0 + cl;
    if (cg < N) smallT[(size_t)(rowbase + cg) * 512 + m0] = f2bf(tile[cl][tlo]);
  }
  if (threadIdx.x < 64){
    float v = sacc[threadIdx.x];
    atomicAdd(&sums6[(blockIdx.y * 64 + threadIdx.x) * 8 + 2 + zi], v);
  }
}

// ---------------- per-n finals -> rbf (2 blocks, one n per thread) ----------------
__global__ __launch_bounds__(256) void finals_kernel(const float* __restrict__ Zcat,
                                                     const float* __restrict__ sums6,
                                                     const float* __restrict__ mom,
                                                     unsigned short* __restrict__ rbf){
  int n = blockIdx.x * 256 + threadIdx.x;
  if (n >= 512) return;
  {
    const float* zrow = Zcat + (size_t)n * ZCAT_COLS;
    float lseHS = __logf(sums6[n * 8 + 0]), lseHW = __logf(sums6[n * 8 + 1]);
    float lse1S = __logf(sums6[n * 8 + 2]), lse1W = __logf(sums6[n * 8 + 3]);
    float lse2S = __logf(sums6[n * 8 + 4]), lse2W = __logf(sums6[n * 8 + 5]);
    float uS[8], uW[8];
    #pragma unroll
    for (int j = 0; j < 8; j++){ uS[j] = zrow[2326 + j]; uW[j] = zrow[2334 + j]; }
    const float* mS = mom; const float* mW = mom + 72;
    float d1 = 0.f, d2 = 0.f, e1 = 0.f, e2 = 0.f;
    #pragma unroll
    for (int a = 0; a < 8; a++){
      d1 += uS[a] * mS[a]; e1 += uW[a] * mW[a];
      #pragma unroll
      for (int b = 0; b < 8; b++){
        d2 += uS[a] * uS[b] * mS[8 + a * 8 + b];
        e2 += uW[a] * uW[b] * mW[8 + a * 8 + b];
      }
    }
    float lse3S = __logf((float)J_SLM + d1 + 0.5f * d2);
    float lse3W = __logf((float)J_WSD + e1 + 0.5f * e2);
    float C3w = (zrow[2005] - lseHW) - lse3W;
    float C3s = (zrow[1002] - lseHS) - lse3S;
    float A1s = zrow[1000] - lseHS - lse1S;
    float A2s = zrow[1001] - lseHS - lse2S;
    float A1w = zrow[2003] - lseHW - lse1W;
    float A2w = zrow[2004] - lseHW - lse2W;
    unsigned short* rr = rbf + n * 32;
    #pragma unroll
    for (int j = 0; j < 8; j++){ rr[j] = f2bf(uW[j]); rr[9 + j] = f2bf(uS[j]); }
    rr[8]  = f2bf(C3w - C8f);
    rr[17] = f2bf(C3s - C17f);
    rr[18] = f2bf(-lseHS - C18f);
    rr[19] = f2bf(A1s - C19f);
    rr[20] = f2bf(A2s - C20f);
    rr[21] = f2bf(-lseHW - C21f);
    rr[22] = f2bf(A1w - C22f);
    rr[23] = f2bf(A2w - C23f);
    #pragma unroll
    for (int j = 24; j < 32; j++) rr[j] = 0;
  }
}

// ---------------- the big output kernel ----------------
// Grid (8,460): blockIdx.x (fastest-varying) carries the n-split (prologue re-reads L3-hot).
// Plain out stores (nt-stores lose L2 write-combining: R4 measured +35MB writes, −90us).
// smallT gathers are bf16 (8B/lane): halves gather traffic + thrash footprint 41->20.5MB.
__global__ __launch_bounds__(256, 4) void final2(
  const unsigned short* __restrict__ rbf, const unsigned short* __restrict__ qbf,
  const float* __restrict__ EP, const int* __restrict__ nsm,
  const uint2* __restrict__ cv, const unsigned short* __restrict__ smallT,
  float* __restrict__ out)
{
  int t = threadIdx.x; int wave = t >> 6; int L = t & 63; int quad = L >> 4; int l16 = L & 15;
  int sbase = blockIdx.y * 256 + wave * 64;
  int nbase = blockIdx.x * 64;
  short8 bfrag[4]; float ep[4]; int cnt[4]; int kmax[4];
  int ccol[4][3]; float cval[4][3];
  #pragma unroll
  for (int j = 0; j < 4; j++){
    int s = sbase + j * 16 + l16;
    bfrag[j] = *(const short8*)(qbf + (size_t)s * 32 + quad * 8);
    ep[j] = EP[s]; cnt[j] = nsm[s];
    #pragma unroll
    for (int k = 0; k < 3; k++){
      uint2 e = cv[(size_t)s * 10 + k];
      ccol[j][k] = (int)e.x; cval[j][k] = __uint_as_float(e.y);
    }
    int kw = cnt[j];
    #pragma unroll
    for (int d = 32; d > 0; d >>= 1){ int o = __shfl_xor(kw, d); kw = (o > kw) ? o : kw; }
    kmax[j] = __builtin_amdgcn_readfirstlane(kw);
  }
  for (int i = 0; i < 4; i++){
    int n0 = nbase + i * 16;
    short8 afrag = *(const short8*)(rbf + (size_t)(n0 + l16) * 32 + quad * 8);
    int nq = n0 + quad * 4;
    #pragma unroll
    for (int j = 0; j < 4; j++){
      f32x4 acc = {0.f, 0.f, 0.f, 0.f};
      acc = __builtin_amdgcn_mfma_f32_16x16x32_bf16(afrag, bfrag[j], acc, 0, 0, 0);
      f32x4 res = acc + ep[j];
      #pragma unroll
      for (int k = 0; k < 3; k++){
        if (k < kmax[j]){                 // wave-uniform skip
          if (k < cnt[j]){                // per-lane mask
            ushort4v q = *(const ushort4v*)(smallT + ((size_t)ccol[j][k] << 9) + nq);
            f32x4 sv = {bf2f(q[0]), bf2f(q[1]), bf2f(q[2]), bf2f(q[3])};
            res += cval[j][k] * sv;
          }
        }
      }
      if (kmax[j] >= 4){                  // rare overflow path (P ~ 1%)
        int s = sbase + j * 16 + l16;
        for (int k = 3; k < 9; k++){
          if (k < cnt[j]){
            uint2 e = cv[(size_t)s * 10 + k];
            ushort4v q = *(const ushort4v*)(smallT + ((size_t)e.x << 9) + nq);
            f32x4 sv = {bf2f(q[0]), bf2f(q[1]), bf2f(q[2]), bf2f(q[3])};
            res += __uint_as_float(e.y) * sv;
          }
        }
      }
      int sj = sbase + j * 16 + l16;
      if (sj < S_TOT){
        #pragma unroll
        for (int r = 0; r < 4; r++)
          out[(size_t)(nq + r) * S_TOT + sj] = res[r];
      }
    }
  }
}

extern "C" void kernel_launch(void* const* d_in, const int* in_sizes, int n_in,
                              void* d_out, int out_size, void* d_ws, size_t ws_size,
                              hipStream_t stream)
{
  const float* x      = (const float*)d_in[0];
  const float* gamma  = (const float*)d_in[1];
  const float* beta   = (const float*)d_in[2];
  const float* dw     = (const float*)d_in[3];
  const float* db     = (const float*)d_in[4];
  const float* h1w    = (const float*)d_in[5];
  const float* h1bias = (const float*)d_in[6];
  const float* h2w    = (const float*)d_in[7];
  const float* h2bias = (const float*)d_in[8];
  const float* whead  = (const float*)d_in[9];
  const float* wt1w1  = (const float*)d_in[10];
  const float* wt1w2  = (const float*)d_in[11];
  const float* wt2w1  = (const float*)d_in[12];
  const float* wt2w2  = (const float*)d_in[13];
  const float* wt3w1  = (const float*)d_in[14];
  const float* wt3w2  = (const float*)d_in[15];
  const float* shead  = (const float*)d_in[16];
  const float* st1w1  = (const float*)d_in[17];
  const float* st1w2  = (const float*)d_in[18];
  const float* st2w1  = (const float*)d_in[19];
  const float* st2w2  = (const float*)d_in[20];
  const float* st3w1  = (const float*)d_in[21];
  const float* st3w2  = (const float*)d_in[22];
  const float* svv    = (const float*)d_in[23];
  const int*   svc    = (const int*)d_in[24];
  float* out = (float*)d_out;

  char* wsb = (char*)d_ws; size_t off = 0;
  auto alloc = [&](size_t bytes) -> void* {
    void* p = wsb + off;
    off = (off + bytes + 255) & ~(size_t)255;
    return p;
  };
  // zero-init region (one memset): colacc | mom | sums6
  float* colacc = (float*)alloc(2048 * 4);
  float* mom    = (float*)alloc(2 * 72 * 4);
  float* sums6  = (float*)alloc(512 * 8 * 4);
  size_t zero_bytes = ((char*)sums6 - (char*)colacc) + 512 * 8 * 4;

  unsigned short* xbn   = (unsigned short*)alloc((size_t)512 * 1024 * 2);
  unsigned short* dwb   = (unsigned short*)alloc((size_t)512 * 1024 * 2);
  unsigned short* h1b   = (unsigned short*)alloc((size_t)512 * 512 * 2);
  unsigned short* h2b   = (unsigned short*)alloc((size_t)512 * 512 * 2);
  unsigned short* wcat  = (unsigned short*)alloc((size_t)ZCAT_COLS * 512 * 2);
  unsigned short* st1b  = (unsigned short*)alloc((size_t)2000 * 128 * 2);
  unsigned short* wt1b  = (unsigned short*)alloc((size_t)2000 * 128 * 2);
  unsigned short* st2b  = (unsigned short*)alloc((size_t)7000 * 32 * 2);
  unsigned short* wt2b  = (unsigned short*)alloc((size_t)7000 * 32 * 2);
  unsigned short* a_bf  = (unsigned short*)alloc((size_t)512 * 512 * 2);
  unsigned short* t_bf  = (unsigned short*)alloc((size_t)512 * 512 * 2);
  unsigned short* h_bf  = (unsigned short*)alloc((size_t)512 * 512 * 2);
  unsigned short* htcat = (unsigned short*)alloc((size_t)512 * 336 * 2);
  float* Zcat  = (float*)alloc((size_t)512 * ZCAT_COLS * 4);
  unsigned short* rbf = (unsigned short*)alloc((size_t)512 * 32 * 2);
  unsigned short* smallT = (unsigned short*)alloc((size_t)20000 * 512 * 2);
  unsigned short* qbf = (unsigned short*)alloc((size_t)S_PAD * 32 * 2);
  float* EP  = (float*)alloc((size_t)S_PAD * 4);
  int*   nsm = (int*)alloc((size_t)S_PAD * 4);
  uint2* cv  = (uint2*)alloc((size_t)S_PAD * 10 * 8);

  (void)in_sizes; (void)n_in; (void)out_size; (void)ws_size;

  hipMemsetAsync(colacc, 0, zero_bytes, stream);
  prep_kernel<<<588, 256, 0, stream>>>(x, colacc, st3w2, wt3w2, mom,
                                       svc, svv, qbf, EP, nsm, cv);
  convert_all<<<14578, 256, 0, stream>>>(
      x, colacc, gamma, beta, xbn, dw, dwb, h1w, h1b, h2w, h2b,
      shead, whead, st1w1, wt1w1, st2w1, wt2w1, st3w1, wt3w1, wcat,
      st1w2, st1b, wt1w2, wt1b, st2w2, st2b, wt2w2, wt2b);

  gemm_mlp<<<dim3(32, 8), 256, 0, stream>>>(xbn, 1024, dwb, db, a_bf, 512, 1024, 0);
  gemm_mlp<<<dim3(32, 8), 256, 0, stream>>>(a_bf, 512, h1b, h1bias, t_bf, 512, 512, 1);
  gemm_mlp<<<dim3(32, 8), 256, 0, stream>>>(t_bf, 512, h2b, h2bias, h_bf, 512, 512, 0);
  gemm_zcat<<<dim3(147, 8), 256, 0, stream>>>(h_bf, wcat, Zcat, htcat, sums6, smallT);
  gemm_tail<<<dim3(284, 8), 256, 0, stream>>>(htcat, st1b, wt1b, st2b, wt2b,
                                              smallT, sums6);
  finals_kernel<<<2, 256, 0, stream>>>(Zcat, sums6, mom, rbf);
  final2<<<dim3(8, 460), 256, 0, stream>>>(rbf, qbf, EP, nsm, cv, smallT, out);
}

// Round 7
// 511.370 us; speedup vs baseline: 1.2453x; 1.0362x over previous
//
#include <hip/hip_runtime.h>
#include <stdint.h>

#define N_ROWS 512
#define D_IN 1024
#define ZCAT_COLS 2342
#define S_TOT 117660
#define S_PAD 117760
#define J_SLM 170000
#define J_WSD 107660

// Centers for bf16 residual storage of per-n constants (exact part goes via fp32 EP[s]).
#define C8f  (-18.49f)   // C3w
#define C17f (-18.95f)   // C3s
#define C18f (-6.91f)    // -lseHS
#define C19f (-14.51f)   // A1s
#define C20f (-15.76f)   // A2s
#define C21f (-6.91f)    // -lseHW
#define C22f (-14.51f)   // A1w
#define C23f (-15.76f)   // A2w

typedef __attribute__((ext_vector_type(8))) short short8;
typedef __attribute__((ext_vector_type(4))) float f32x4;
typedef __attribute__((ext_vector_type(4))) unsigned short ushort4v;

__device__ inline unsigned short f2bf(float f){
  unsigned int u = __float_as_uint(f);
  u += 0x7FFF + ((u >> 16) & 1);
  return (unsigned short)(u >> 16);
}
__device__ inline float bf2f(unsigned short u){
  return __uint_as_float((unsigned int)u << 16);
}

// ---------------- merged prep: bn partials | tail-3 moments | per-sense q build ----------------
// blocks [0,64): BN partial sums; [64,128): moments; [128,588): build_q. All independent.
__global__ __launch_bounds__(256) void prep_kernel(
  const float* __restrict__ x, float* __restrict__ colacc,
  const float* __restrict__ wS, const float* __restrict__ wW, float* __restrict__ mom,
  const int* __restrict__ sv_cols, const float* __restrict__ sv_vals,
  unsigned short* __restrict__ qbf, float* __restrict__ EP, int* __restrict__ nsm,
  uint2* __restrict__ cv)
{
  int b = blockIdx.x;
  __shared__ float lds[4][72];
  if (b < 64){
    // ---- BN partial sums ----
    int r0 = b * 8;
    int t = threadIdx.x;
    #pragma unroll
    for (int q = 0; q < 4; q++){
      int j = t + q * 256;
      float s1 = 0.f, s2 = 0.f;
      #pragma unroll
      for (int r = 0; r < 8; r++){
        float v = x[(size_t)(r0 + r) * D_IN + j];
        s1 += v; s2 += v * v;
      }
      atomicAdd(&colacc[j], s1);
      atomicAdd(&colacc[1024 + j], s2);
    }
    return;
  }
  if (b < 128){
    // ---- moments: 32 x-blocks per side ----
    int bb = b - 64;
    int side = bb >> 5;          // 0: SLM(wS), 1: WSD(wW)
    int xb = bb & 31;
    const float* w2 = side ? wW : wS;
    int J = side ? J_WSD : J_SLM;
    float* outp = mom + side * 72;
    float s1[8]; float m2[64];
    #pragma unroll
    for (int e = 0; e < 8; e++) s1[e] = 0.f;
    #pragma unroll
    for (int e = 0; e < 64; e++) m2[e] = 0.f;
    for (int r = xb * 256 + threadIdx.x; r < J; r += 32 * 256){
      const f32x4* p = (const f32x4*)(w2 + (size_t)r * 8);
      f32x4 wa = p[0], wb = p[1];
      float w[8] = {wa[0], wa[1], wa[2], wa[3], wb[0], wb[1], wb[2], wb[3]};
      #pragma unroll
      for (int a = 0; a < 8; a++){
        s1[a] += w[a];
        #pragma unroll
        for (int bq = 0; bq < 8; bq++) m2[a * 8 + bq] += w[a] * w[bq];
      }
    }
    int L = threadIdx.x & 63; int wave = threadIdx.x >> 6;
    #pragma unroll
    for (int e = 0; e < 72; e++){
      float v = (e < 8) ? s1[e] : m2[e - 8];
      #pragma unroll
      for (int d = 32; d > 0; d >>= 1) v += __shfl_down(v, d);
      if (L == 0) lds[wave][e] = v;
    }
    __syncthreads();
    int tt = threadIdx.x;
    if (tt < 72){
      float v = lds[0][tt] + lds[1][tt] + lds[2][tt] + lds[3][tt];
      atomicAdd(&outp[tt], v);
    }
    return;
  }
  // ---- build_q ----
  int s = (b - 128) * 256 + threadIdx.x;
  if (s >= S_PAD) return;
  unsigned short qr[32];
  #pragma unroll
  for (int e = 0; e < 32; e++) qr[e] = 0;
  uint2 pairs[10];
  #pragma unroll
  for (int e = 0; e < 10; e++){ pairs[e].x = 0; pairs[e].y = 0; }
  int idx = 0; float cw = 0.f, vh = 0.f, v1s = 0.f, v2s = 0.f;
  float w8[8];
  #pragma unroll
  for (int e = 0; e < 8; e++) w8[e] = 0.f;
  if (s < S_TOT){
    if (s < 10000){ pairs[0].x = (unsigned)(10000 + s); pairs[0].y = __float_as_uint(1.0f); idx = 1; }
    #pragma unroll
    for (int k = 0; k < 8; k++){
      int c = sv_cols[(size_t)s * 8 + k];
      float v = 0.1f * sv_vals[(size_t)s * 8 + k];
      if (c >= 10000){
        cw += v;
        const float* wr = wS + (size_t)(c - 10000) * 8;
        #pragma unroll
        for (int j = 0; j < 8; j++) w8[j] += v * wr[j];
      } else {
        pairs[idx].x = (unsigned)c; pairs[idx].y = __float_as_uint(v); idx++;
        if (c < 1000) vh += v; else if (c < 3000) v1s += v; else v2s += v;
      }
    }
    if (s >= 10000){
      const float* wrw = wW + (size_t)(s - 10000) * 8;
      #pragma unroll
      for (int j = 0; j < 8; j++) qr[j] = f2bf(wrw[j]);
      qr[8] = f2bf(1.0f);
    }
    #pragma unroll
    for (int j = 0; j < 8; j++) qr[9 + j] = f2bf(w8[j]);
    qr[17] = f2bf(cw); qr[18] = f2bf(vh); qr[19] = f2bf(v1s); qr[20] = f2bf(v2s);
    qr[21] = f2bf(s < 1000 ? 1.f : 0.f);
    qr[22] = f2bf((s >= 1000 && s < 3000) ? 1.f : 0.f);
    qr[23] = f2bf((s >= 3000 && s < 10000) ? 1.f : 0.f);
    float ep = (s >= 10000) ? C8f : (s < 1000 ? C21f : (s < 3000 ? C22f : C23f));
    ep += cw * C17f + vh * C18f + v1s * C19f + v2s * C20f;
    EP[s] = ep;
  } else {
    EP[s] = 0.f;
  }
  nsm[s] = idx;
  #pragma unroll
  for (int e = 0; e < 10; e++) cv[(size_t)s * 10 + e] = pairs[e];
  short8* qp = (short8*)(qbf + (size_t)s * 32);
  const short8* src = (const short8*)qr;
  qp[0] = src[0]; qp[1] = src[1]; qp[2] = src[2]; qp[3] = src[3];
}

// ---------------- fp32 -> bf16 conversion of everything (BN finalize inlined) ----------------
__global__ void convert_all(
  const float* __restrict__ x, const float* __restrict__ colacc,
  const float* __restrict__ gamma, const float* __restrict__ beta, unsigned short* __restrict__ xbn,
  const float* __restrict__ dw, unsigned short* __restrict__ dwb,
  const float* __restrict__ h1w, unsigned short* __restrict__ h1b,
  const float* __restrict__ h2w, unsigned short* __restrict__ h2b,
  const float* __restrict__ sh, const float* __restrict__ wh,
  const float* __restrict__ s11, const float* __restrict__ w11,
  const float* __restrict__ s21, const float* __restrict__ w21,
  const float* __restrict__ s31, const float* __restrict__ w31, unsigned short* __restrict__ wcat,
  const float* __restrict__ st1w2, unsigned short* __restrict__ st1b,
  const float* __restrict__ wt1w2, unsigned short* __restrict__ wt1b,
  const float* __restrict__ st2w2, unsigned short* __restrict__ st2b,
  const float* __restrict__ wt2w2, unsigned short* __restrict__ wt2b)
{
  size_t i = (size_t)blockIdx.x * 256 + threadIdx.x;
  const size_t o1 = 524288, o2 = o1 + 524288, o3 = o2 + 262144, o4 = o3 + 262144,
               o5 = o4 + 1199104, o6 = o5 + 256000, o7 = o6 + 256000, o8 = o7 + 224000,
               o9 = o8 + 224000;
  if (i < o1){
    int c = (int)(i & 1023);
    float mu = colacc[c] * (1.0f / 512.0f);
    float var = colacc[1024 + c] * (1.0f / 512.0f) - mu * mu;
    float sc = rsqrtf(var + 1e-5f) * gamma[c];
    float shv = beta[c] - mu * sc;
    xbn[i] = f2bf(x[i] * sc + shv);
  }
  else if (i < o2){ size_t l = i - o1; dwb[l] = f2bf(dw[l]); }
  else if (i < o3){ size_t l = i - o2; h1b[l] = f2bf(h1w[l]); }
  else if (i < o4){ size_t l = i - o3; h2b[l] = f2bf(h2w[l]); }
  else if (i < o5){
    size_t l = i - o4;
    float v;
    if (l < 513536) v = sh[l];
    else if (l < 1027072) v = wh[l - 513536];
    else if (l < 1092608) v = s11[l - 1027072];
    else if (l < 1158144) v = w11[l - 1092608];
    else if (l < 1174528) v = s21[l - 1158144];
    else if (l < 1190912) v = w21[l - 1174528];
    else if (l < 1195008) v = s31[l - 1190912];
    else v = w31[l - 1195008];
    wcat[l] = f2bf(v);
  }
  else if (i < o6){ size_t l = i - o5; st1b[l] = f2bf(st1w2[l]); }
  else if (i < o7){ size_t l = i - o6; wt1b[l] = f2bf(wt1w2[l]); }
  else if (i < o8){ size_t l = i - o7; st2b[l] = f2bf(st2w2[l]); }
  else if (i < o9){ size_t l = i - o8; wt2b[l] = f2bf(wt2w2[l]); }
}

// ---------------- MLP NT bf16 MFMA GEMM: C[m,n] = sum_k A[m,k]*B[n,k] -> bf16 ----------------
__global__ __launch_bounds__(256) void gemm_mlp(
  const unsigned short* __restrict__ A, int lda, const unsigned short* __restrict__ B,
  const float* __restrict__ bias, unsigned short* __restrict__ outB,
  int N, int K, int relu)
{
  int t = threadIdx.x; int wave = t >> 6; int L = t & 63; int quad = L >> 4; int l16 = L & 15;
  int mbase = blockIdx.y * 64 + wave * 16;
  int nb0 = blockIdx.x * 16;
  f32x4 acc = {0,0,0,0};
  int mrow = mbase + l16;
  const unsigned short* Ap = A + (size_t)mrow * lda + quad * 8;
  int nn = nb0 + l16;
  if (nn > N - 1) nn = N - 1;
  const unsigned short* Bp = B + (size_t)nn * K + quad * 8;
  for (int k0 = 0; k0 < K; k0 += 32){
    short8 a = *(const short8*)(Ap + k0);
    short8 b = *(const short8*)(Bp + k0);
    acc = __builtin_amdgcn_mfma_f32_16x16x32_bf16(a, b, acc, 0, 0, 0);
  }
  int n = nb0 + l16;
  if (n < N){
    float bv = bias ? bias[n] : 0.0f;
    #pragma unroll
    for (int r = 0; r < 4; r++){
      int m = mbase + quad * 4 + r;
      float v = acc[r] + bv;
      if (relu) v = fmaxf(v, 0.0f);
      outB[(size_t)m * N + n] = f2bf(v);
    }
  }
}

// ---------------- Zcat GEMM + head exp-sums + htcat + FUSED head transpose into smallT ----------
// smallT is bf16 (raw logits |v|<~2, bf16 err ~0.004 << absmax 0.125).
__global__ __launch_bounds__(256) void gemm_zcat(
  const unsigned short* __restrict__ A, const unsigned short* __restrict__ B,
  float* __restrict__ Zcat, unsigned short* __restrict__ htcat, float* __restrict__ sums6,
  unsigned short* __restrict__ smallT)
{
  const int N = ZCAT_COLS, K = 512;
  int t = threadIdx.x; int wave = t >> 6; int L = t & 63; int quad = L >> 4; int l16 = L & 15;
  int mbase = blockIdx.y * 64 + wave * 16;
  int nb0 = blockIdx.x * 16;
  f32x4 acc = {0,0,0,0};
  int mrow = mbase + l16;
  const unsigned short* Ap = A + (size_t)mrow * 512 + quad * 8;
  int nn = nb0 + l16;
  if (nn > N - 1) nn = N - 1;
  const unsigned short* Bp = B + (size_t)nn * K + quad * 8;
  for (int k0 = 0; k0 < K; k0 += 32){
    short8 a = *(const short8*)(Ap + k0);
    short8 b = *(const short8*)(Bp + k0);
    acc = __builtin_amdgcn_mfma_f32_16x16x32_bf16(a, b, acc, 0, 0, 0);
  }
  bool doEps = (nb0 < 2006);
  __shared__ float sacc[64][2];
  __shared__ float tile[16][65];
  if (doEps){
    for (int e = threadIdx.x; e < 128; e += 256) ((float*)sacc)[e] = 0.f;
    __syncthreads();
  }
  int c = nb0 + l16;
  #pragma unroll
  for (int r = 0; r < 4; r++){
    int m = mbase + quad * 4 + r;
    float v = acc[r];
    if (c < N){
      bool zkeep = (c >= 1000 && c < 1003) || (c >= 2003 && c < 2006) || (c >= 2326);
      if (zkeep) Zcat[(size_t)m * ZCAT_COLS + c] = v;
      if (c >= 2006) htcat[(size_t)m * 336 + (c - 2006)] = f2bf(v);
    }
    if (doEps){
      float e0 = (c < 1003) ? __expf(v) : 0.f;
      float e1 = (c >= 1003 && c < 2006) ? __expf(v) : 0.f;
      #pragma unroll
      for (int d = 8; d > 0; d >>= 1){ e0 += __shfl_xor(e0, d); e1 += __shfl_xor(e1, d); }
      if (l16 == 0){
        int mr = wave * 16 + quad * 4 + r;
        if (e0 != 0.f) atomicAdd(&sacc[mr][0], e0);
        if (e1 != 0.f) atomicAdd(&sacc[mr][1], e1);
      }
    }
  }
  bool doT = (nb0 < 2003);   // block-uniform
  if (doT){
    #pragma unroll
    for (int r = 0; r < 4; r++)
      tile[l16][wave * 16 + quad * 4 + r] = acc[r];
    __syncthreads();
    int tlo = t & 63, thi = t >> 6;
    int m0 = blockIdx.y * 64;
    #pragma unroll
    for (int p = 0; p < 4; p++){
      int cl = thi + p * 4;
      int cg = nb0 + cl;
      int row = -1;
      if (cg < 1000) row = cg;                              // S-side head
      else if (cg >= 1003 && cg < 2003) row = 10000 + (cg - 1003);  // W-side head
      if (row >= 0) smallT[(size_t)row * 512 + m0 + tlo] = f2bf(tile[cl][tlo]);
    }
  }
  if (doEps){
    __syncthreads();
    int tt = threadIdx.x;
    if (tt < 128){
      int mr = tt >> 1;
      float v = sacc[mr][tt & 1];
      if (v != 0.f) atomicAdd(&sums6[(blockIdx.y * 64 + mr) * 8 + (tt & 1)], v);
    }
  }
}

// ---------------- merged tail GEMMs + exp-sums + FUSED transposed bf16 write into smallT ----------
// Flattened grid: bx in [0,32) zi=0; [32,64) zi=1; [64,174) zi=2; [174,284) zi=3 (no dead blocks).
// smallT row bases: z1S->1000, z1W->11000, z2S->3000, z2W->13000.
__global__ __launch_bounds__(256) void gemm_tail(
  const unsigned short* __restrict__ htcat,
  const unsigned short* __restrict__ b0, const unsigned short* __restrict__ b1,
  const unsigned short* __restrict__ b2, const unsigned short* __restrict__ b3,
  unsigned short* __restrict__ smallT, float* __restrict__ sums6)
{
  int bx = blockIdx.x;
  int zi, nbx;
  if (bx < 32){ zi = 0; nbx = bx; }
  else if (bx < 64){ zi = 1; nbx = bx - 32; }
  else if (bx < 174){ zi = 2; nbx = bx - 64; }
  else { zi = 3; nbx = bx - 174; }
  int N = (zi < 2) ? 2000 : 7000;
  int K = (zi < 2) ? 128 : 32;
  int aoff = (zi == 0) ? 0 : (zi == 1) ? 128 : (zi == 2) ? 256 : 288;
  int rowbase = (zi == 0) ? 1000 : (zi == 1) ? 11000 : (zi == 2) ? 3000 : 13000;
  const unsigned short* B = (zi == 0) ? b0 : (zi == 1) ? b1 : (zi == 2) ? b2 : b3;
  int nb0 = nbx * 64;
  int t = threadIdx.x; int wave = t >> 6; int L = t & 63; int quad = L >> 4; int l16 = L & 15;
  int mbase = blockIdx.y * 64 + wave * 16;
  f32x4 acc[4] = {{0,0,0,0},{0,0,0,0},{0,0,0,0},{0,0,0,0}};
  int mrow = mbase + l16;
  const unsigned short* Ap = htcat + (size_t)mrow * 336 + aoff + quad * 8;
  const unsigned short* Bp[4];
  #pragma unroll
  for (int j = 0; j < 4; j++){
    int n = nb0 + j * 16 + l16;
    if (n > N - 1) n = N - 1;
    Bp[j] = B + (size_t)n * K + quad * 8;
  }
  for (int k0 = 0; k0 < K; k0 += 32){
    short8 a = *(const short8*)(Ap + k0);
    #pragma unroll
    for (int j = 0; j < 4; j++){
      short8 b = *(const short8*)(Bp[j] + k0);
      acc[j] = __builtin_amdgcn_mfma_f32_16x16x32_bf16(a, b, acc[j], 0, 0, 0);
    }
  }
  __shared__ float sacc[64];
  __shared__ float tile[64][65];
  for (int e = threadIdx.x; e < 64; e += 256) sacc[e] = 0.f;
  __syncthreads();
  #pragma unroll
  for (int j = 0; j < 4; j++){
    int n = nb0 + j * 16 + l16;
    #pragma unroll
    for (int r = 0; r < 4; r++){
      int mloc = wave * 16 + quad * 4 + r;
      float v = acc[j][r];
      tile[j * 16 + l16][mloc] = v;
      float e = (n < N) ? __expf(v) : 0.f;
      #pragma unroll
      for (int d = 8; d > 0; d >>= 1) e += __shfl_xor(e, d);
      if (l16 == 0) atomicAdd(&sacc[mloc], e);
    }
  }
  __syncthreads();
  // transposed write-out: 64 c-rows x 64 m-cols, coalesced along m (bf16)
  int tlo = t & 63, thi = t >> 6;
  int m0 = blockIdx.y * 64 + tlo;
  #pragma unroll
  for (int p = 0; p < 16; p++){
    int cl = thi + p * 4;
    int cg = nb0 + cl;
    if (cg < N) smallT[(size_t)(rowbase + cg) * 512 + m0] = f2bf(tile[cl][tlo]);
  }
  if (threadIdx.x < 64){
    float v = sacc[threadIdx.x];
    atomicAdd(&sums6[(blockIdx.y * 64 + threadIdx.x) * 8 + 2 + zi], v);
  }
}

// ---------------- per-n finals -> rbf (2 blocks, one n per thread) ----------------
__global__ __launch_bounds__(256) void finals_kernel(const float* __restrict__ Zcat,
                                                     const float* __restrict__ sums6,
                                                     const float* __restrict__ mom,
                                                     unsigned short* __restrict__ rbf){
  int n = blockIdx.x * 256 + threadIdx.x;
  if (n >= 512) return;
  {
    const float* zrow = Zcat + (size_t)n * ZCAT_COLS;
    float lseHS = __logf(sums6[n * 8 + 0]), lseHW = __logf(sums6[n * 8 + 1]);
    float lse1S = __logf(sums6[n * 8 + 2]), lse1W = __logf(sums6[n * 8 + 3]);
    float lse2S = __logf(sums6[n * 8 + 4]), lse2W = __logf(sums6[n * 8 + 5]);
    float uS[8], uW[8];
    #pragma unroll
    for (int j = 0; j < 8; j++){ uS[j] = zrow[2326 + j]; uW[j] = zrow[2334 + j]; }
    const float* mS = mom; const float* mW = mom + 72;
    float d1 = 0.f, d2 = 0.f, e1 = 0.f, e2 = 0.f;
    #pragma unroll
    for (int a = 0; a < 8; a++){
      d1 += uS[a] * mS[a]; e1 += uW[a] * mW[a];
      #pragma unroll
      for (int b = 0; b < 8; b++){
        d2 += uS[a] * uS[b] * mS[8 + a * 8 + b];
        e2 += uW[a] * uW[b] * mW[8 + a * 8 + b];
      }
    }
    float lse3S = __logf((float)J_SLM + d1 + 0.5f * d2);
    float lse3W = __logf((float)J_WSD + e1 + 0.5f * e2);
    float C3w = (zrow[2005] - lseHW) - lse3W;
    float C3s = (zrow[1002] - lseHS) - lse3S;
    float A1s = zrow[1000] - lseHS - lse1S;
    float A2s = zrow[1001] - lseHS - lse2S;
    float A1w = zrow[2003] - lseHW - lse1W;
    float A2w = zrow[2004] - lseHW - lse2W;
    unsigned short* rr = rbf + n * 32;
    #pragma unroll
    for (int j = 0; j < 8; j++){ rr[j] = f2bf(uW[j]); rr[9 + j] = f2bf(uS[j]); }
    rr[8]  = f2bf(C3w - C8f);
    rr[17] = f2bf(C3s - C17f);
    rr[18] = f2bf(-lseHS - C18f);
    rr[19] = f2bf(A1s - C19f);
    rr[20] = f2bf(A2s - C20f);
    rr[21] = f2bf(-lseHW - C21f);
    rr[22] = f2bf(A1w - C22f);
    rr[23] = f2bf(A2w - C23f);
    #pragma unroll
    for (int j = 24; j < 32; j++) rr[j] = 0;
  }
}

// ---------------- the big output kernel ----------------
// Grid (8,460): blockIdx.x (fastest-varying) carries the n-split (prologue re-reads L3-hot).
// smallT gathers bf16 (8B/lane). NEW: LDS-staged epilogue — res tiles staged in [16][260]
// LDS, drained as aligned float4 stores (16 insts/thread vs 64 scalar): 4x fewer VMEM
// store issues + perfect intra-instruction coalescing (final2 ran at 1.8-2.4 TB/s,
// far under BW ceiling with VALU ~4% -> store issue/queue pressure is the suspect).
__global__ __launch_bounds__(256, 4) void final2(
  const unsigned short* __restrict__ rbf, const unsigned short* __restrict__ qbf,
  const float* __restrict__ EP, const int* __restrict__ nsm,
  const uint2* __restrict__ cv, const unsigned short* __restrict__ smallT,
  float* __restrict__ out)
{
  int t = threadIdx.x; int wave = t >> 6; int L = t & 63; int quad = L >> 4; int l16 = L & 15;
  int sbase = blockIdx.y * 256 + wave * 64;
  int nbase = blockIdx.x * 64;
  __shared__ float ot[16][260];   // 16 n-rows x 256 s-cols (+4 pad): 16.6KB, 8 blocks/CU ok
  short8 bfrag[4]; float ep[4]; int cnt[4]; int kmax[4];
  int ccol[4][3]; float cval[4][3];
  #pragma unroll
  for (int j = 0; j < 4; j++){
    int s = sbase + j * 16 + l16;
    bfrag[j] = *(const short8*)(qbf + (size_t)s * 32 + quad * 8);
    ep[j] = EP[s]; cnt[j] = nsm[s];
    #pragma unroll
    for (int k = 0; k < 3; k++){
      uint2 e = cv[(size_t)s * 10 + k];
      ccol[j][k] = (int)e.x; cval[j][k] = __uint_as_float(e.y);
    }
    int kw = cnt[j];
    #pragma unroll
    for (int d = 32; d > 0; d >>= 1){ int o = __shfl_xor(kw, d); kw = (o > kw) ? o : kw; }
    kmax[j] = __builtin_amdgcn_readfirstlane(kw);
  }
  int trow = t >> 4;               // 0..15 (drain row)
  int tcol = (t & 15) * 16;        // 0..240 step 16 (drain col base)
  int sblk = blockIdx.y * 256;     // block s-window base
  for (int i = 0; i < 4; i++){
    int n0 = nbase + i * 16;
    short8 afrag = *(const short8*)(rbf + (size_t)(n0 + l16) * 32 + quad * 8);
    int nq = n0 + quad * 4;
    #pragma unroll
    for (int j = 0; j < 4; j++){
      f32x4 acc = {0.f, 0.f, 0.f, 0.f};
      acc = __builtin_amdgcn_mfma_f32_16x16x32_bf16(afrag, bfrag[j], acc, 0, 0, 0);
      f32x4 res = acc + ep[j];
      #pragma unroll
      for (int k = 0; k < 3; k++){
        if (k < kmax[j]){                 // wave-uniform skip
          if (k < cnt[j]){                // per-lane mask
            ushort4v q = *(const ushort4v*)(smallT + ((size_t)ccol[j][k] << 9) + nq);
            f32x4 sv = {bf2f(q[0]), bf2f(q[1]), bf2f(q[2]), bf2f(q[3])};
            res += cval[j][k] * sv;
          }
        }
      }
      if (kmax[j] >= 4){                  // rare overflow path (P ~ 1%)
        int s = sbase + j * 16 + l16;
        for (int k = 3; k < 9; k++){
          if (k < cnt[j]){
            uint2 e = cv[(size_t)s * 10 + k];
            ushort4v q = *(const ushort4v*)(smallT + ((size_t)e.x << 9) + nq);
            f32x4 sv = {bf2f(q[0]), bf2f(q[1]), bf2f(q[2]), bf2f(q[3])};
            res += __uint_as_float(e.y) * sv;
          }
        }
      }
      // stage into LDS: row = local n (quad*4+r), col = wave*64 + j*16 + l16
      int lc = wave * 64 + j * 16 + l16;
      #pragma unroll
      for (int r = 0; r < 4; r++)
        ot[quad * 4 + r][lc] = res[r];
    }
    __syncthreads();
    // drain: thread t writes row (t>>4), 4 x float4 at cols (t&15)*16 + cc*4
    {
      size_t rowoff = (size_t)(n0 + trow) * S_TOT;
      #pragma unroll
      for (int cc = 0; cc < 4; cc++){
        int scol = sblk + tcol + cc * 4;
        if (scol < S_TOT){
          f32x4 v = *(const f32x4*)&ot[trow][tcol + cc * 4];
          *(f32x4*)&out[rowoff + scol] = v;
        }
      }
    }
    __syncthreads();
  }
}

extern "C" void kernel_launch(void* const* d_in, const int* in_sizes, int n_in,
                              void* d_out, int out_size, void* d_ws, size_t ws_size,
                              hipStream_t stream)
{
  const float* x      = (const float*)d_in[0];
  const float* gamma  = (const float*)d_in[1];
  const float* beta   = (const float*)d_in[2];
  const float* dw     = (const float*)d_in[3];
  const float* db     = (const float*)d_in[4];
  const float* h1w    = (const float*)d_in[5];
  const float* h1bias = (const float*)d_in[6];
  const float* h2w    = (const float*)d_in[7];
  const float* h2bias = (const float*)d_in[8];
  const float* whead  = (const float*)d_in[9];
  const float* wt1w1  = (const float*)d_in[10];
  const float* wt1w2  = (const float*)d_in[11];
  const float* wt2w1  = (const float*)d_in[12];
  const float* wt2w2  = (const float*)d_in[13];
  const float* wt3w1  = (const float*)d_in[14];
  const float* wt3w2  = (const float*)d_in[15];
  const float* shead  = (const float*)d_in[16];
  const float* st1w1  = (const float*)d_in[17];
  const float* st1w2  = (const float*)d_in[18];
  const float* st2w1  = (const float*)d_in[19];
  const float* st2w2  = (const float*)d_in[20];
  const float* st3w1  = (const float*)d_in[21];
  const float* st3w2  = (const float*)d_in[22];
  const float* svv    = (const float*)d_in[23];
  const int*   svc    = (const int*)d_in[24];
  float* out = (float*)d_out;

  char* wsb = (char*)d_ws; size_t off = 0;
  auto alloc = [&](size_t bytes) -> void* {
    void* p = wsb + off;
    off = (off + bytes + 255) & ~(size_t)255;
    return p;
  };
  // zero-init region (one memset): colacc | mom | sums6
  float* colacc = (float*)alloc(2048 * 4);
  float* mom    = (float*)alloc(2 * 72 * 4);
  float* sums6  = (float*)alloc(512 * 8 * 4);
  size_t zero_bytes = ((char*)sums6 - (char*)colacc) + 512 * 8 * 4;

  unsigned short* xbn   = (unsigned short*)alloc((size_t)512 * 1024 * 2);
  unsigned short* dwb   = (unsigned short*)alloc((size_t)512 * 1024 * 2);
  unsigned short* h1b   = (unsigned short*)alloc((size_t)512 * 512 * 2);
  unsigned short* h2b   = (unsigned short*)alloc((size_t)512 * 512 * 2);
  unsigned short* wcat  = (unsigned short*)alloc((size_t)ZCAT_COLS * 512 * 2);
  unsigned short* st1b  = (unsigned short*)alloc((size_t)2000 * 128 * 2);
  unsigned short* wt1b  = (unsigned short*)alloc((size_t)2000 * 128 * 2);
  unsigned short* st2b  = (unsigned short*)alloc((size_t)7000 * 32 * 2);
  unsigned short* wt2b  = (unsigned short*)alloc((size_t)7000 * 32 * 2);
  unsigned short* a_bf  = (unsigned short*)alloc((size_t)512 * 512 * 2);
  unsigned short* t_bf  = (unsigned short*)alloc((size_t)512 * 512 * 2);
  unsigned short* h_bf  = (unsigned short*)alloc((size_t)512 * 512 * 2);
  unsigned short* htcat = (unsigned short*)alloc((size_t)512 * 336 * 2);
  float* Zcat  = (float*)alloc((size_t)512 * ZCAT_COLS * 4);
  unsigned short* rbf = (unsigned short*)alloc((size_t)512 * 32 * 2);
  unsigned short* smallT = (unsigned short*)alloc((size_t)20000 * 512 * 2);
  unsigned short* qbf = (unsigned short*)alloc((size_t)S_PAD * 32 * 2);
  float* EP  = (float*)alloc((size_t)S_PAD * 4);
  int*   nsm = (int*)alloc((size_t)S_PAD * 4);
  uint2* cv  = (uint2*)alloc((size_t)S_PAD * 10 * 8);

  (void)in_sizes; (void)n_in; (void)out_size; (void)ws_size;

  hipMemsetAsync(colacc, 0, zero_bytes, stream);
  prep_kernel<<<588, 256, 0, stream>>>(x, colacc, st3w2, wt3w2, mom,
                                       svc, svv, qbf, EP, nsm, cv);
  convert_all<<<14578, 256, 0, stream>>>(
      x, colacc, gamma, beta, xbn, dw, dwb, h1w, h1b, h2w, h2b,
      shead, whead, st1w1, wt1w1, st2w1, wt2w1, st3w1, wt3w1, wcat,
      st1w2, st1b, wt1w2, wt1b, st2w2, st2b, wt2w2, wt2b);

  gemm_mlp<<<dim3(32, 8), 256, 0, stream>>>(xbn, 1024, dwb, db, a_bf, 512, 1024, 0);
  gemm_mlp<<<dim3(32, 8), 256, 0, stream>>>(a_bf, 512, h1b, h1bias, t_bf, 512, 512, 1);
  gemm_mlp<<<dim3(32, 8), 256, 0, stream>>>(t_bf, 512, h2b, h2bias, h_bf, 512, 512, 0);
  gemm_zcat<<<dim3(147, 8), 256, 0, stream>>>(h_bf, wcat, Zcat, htcat, sums6, smallT);
  gemm_tail<<<dim3(284, 8), 256, 0, stream>>>(htcat, st1b, wt1b, st2b, wt2b,
                                              smallT, sums6);
  finals_kernel<<<2, 256, 0, stream>>>(Zcat, sums6, mom, rbf);
  final2<<<dim3(8, 460), 256, 0, stream>>>(rbf, qbf, EP, nsm, cv, smallT, out);
}

// Round 8
// 509.662 us; speedup vs baseline: 1.2495x; 1.0034x over previous
//
#include <hip/hip_runtime.h>
#include <stdint.h>

#define N_ROWS 512
#define D_IN 1024
#define ZCAT_COLS 2342
#define S_TOT 117660
#define S_PAD 117760
#define J_SLM 170000
#define J_WSD 107660

// Centers for bf16 residual storage of per-n constants (exact part goes via fp32 EP[s]).
#define C8f  (-18.49f)   // C3w
#define C17f (-18.95f)   // C3s
#define C18f (-6.91f)    // -lseHS
#define C19f (-14.51f)   // A1s
#define C20f (-15.76f)   // A2s
#define C21f (-6.91f)    // -lseHW
#define C22f (-14.51f)   // A1w
#define C23f (-15.76f)   // A2w

typedef __attribute__((ext_vector_type(8))) short short8;
typedef __attribute__((ext_vector_type(4))) float f32x4;
typedef __attribute__((ext_vector_type(4))) unsigned short ushort4v;

__device__ inline unsigned short f2bf(float f){
  unsigned int u = __float_as_uint(f);
  u += 0x7FFF + ((u >> 16) & 1);
  return (unsigned short)(u >> 16);
}
__device__ inline float bf2f(unsigned short u){
  return __uint_as_float((unsigned int)u << 16);
}

// ---------------- merged prep: bn partials | tail-3 moments | per-sense q build ----------------
// blocks [0,64): BN partial sums; [64,128): moments; [128,588): build_q. All independent.
__global__ __launch_bounds__(256) void prep_kernel(
  const float* __restrict__ x, float* __restrict__ colacc,
  const float* __restrict__ wS, const float* __restrict__ wW, float* __restrict__ mom,
  const int* __restrict__ sv_cols, const float* __restrict__ sv_vals,
  unsigned short* __restrict__ qbf, float* __restrict__ EP, int* __restrict__ nsm,
  uint2* __restrict__ cv)
{
  int b = blockIdx.x;
  __shared__ float lds[4][72];
  if (b < 64){
    // ---- BN partial sums ----
    int r0 = b * 8;
    int t = threadIdx.x;
    #pragma unroll
    for (int q = 0; q < 4; q++){
      int j = t + q * 256;
      float s1 = 0.f, s2 = 0.f;
      #pragma unroll
      for (int r = 0; r < 8; r++){
        float v = x[(size_t)(r0 + r) * D_IN + j];
        s1 += v; s2 += v * v;
      }
      atomicAdd(&colacc[j], s1);
      atomicAdd(&colacc[1024 + j], s2);
    }
    return;
  }
  if (b < 128){
    // ---- moments: 32 x-blocks per side ----
    int bb = b - 64;
    int side = bb >> 5;          // 0: SLM(wS), 1: WSD(wW)
    int xb = bb & 31;
    const float* w2 = side ? wW : wS;
    int J = side ? J_WSD : J_SLM;
    float* outp = mom + side * 72;
    float s1[8]; float m2[64];
    #pragma unroll
    for (int e = 0; e < 8; e++) s1[e] = 0.f;
    #pragma unroll
    for (int e = 0; e < 64; e++) m2[e] = 0.f;
    for (int r = xb * 256 + threadIdx.x; r < J; r += 32 * 256){
      const f32x4* p = (const f32x4*)(w2 + (size_t)r * 8);
      f32x4 wa = p[0], wb = p[1];
      float w[8] = {wa[0], wa[1], wa[2], wa[3], wb[0], wb[1], wb[2], wb[3]};
      #pragma unroll
      for (int a = 0; a < 8; a++){
        s1[a] += w[a];
        #pragma unroll
        for (int bq = 0; bq < 8; bq++) m2[a * 8 + bq] += w[a] * w[bq];
      }
    }
    int L = threadIdx.x & 63; int wave = threadIdx.x >> 6;
    #pragma unroll
    for (int e = 0; e < 72; e++){
      float v = (e < 8) ? s1[e] : m2[e - 8];
      #pragma unroll
      for (int d = 32; d > 0; d >>= 1) v += __shfl_down(v, d);
      if (L == 0) lds[wave][e] = v;
    }
    __syncthreads();
    int tt = threadIdx.x;
    if (tt < 72){
      float v = lds[0][tt] + lds[1][tt] + lds[2][tt] + lds[3][tt];
      atomicAdd(&outp[tt], v);
    }
    return;
  }
  // ---- build_q ----
  int s = (b - 128) * 256 + threadIdx.x;
  if (s >= S_PAD) return;
  unsigned short qr[32];
  #pragma unroll
  for (int e = 0; e < 32; e++) qr[e] = 0;
  uint2 pairs[10];
  #pragma unroll
  for (int e = 0; e < 10; e++){ pairs[e].x = 0; pairs[e].y = 0; }
  int idx = 0; float cw = 0.f, vh = 0.f, v1s = 0.f, v2s = 0.f;
  float w8[8];
  #pragma unroll
  for (int e = 0; e < 8; e++) w8[e] = 0.f;
  if (s < S_TOT){
    if (s < 10000){ pairs[0].x = (unsigned)(10000 + s); pairs[0].y = __float_as_uint(1.0f); idx = 1; }
    #pragma unroll
    for (int k = 0; k < 8; k++){
      int c = sv_cols[(size_t)s * 8 + k];
      float v = 0.1f * sv_vals[(size_t)s * 8 + k];
      if (c >= 10000){
        cw += v;
        const float* wr = wS + (size_t)(c - 10000) * 8;
        #pragma unroll
        for (int j = 0; j < 8; j++) w8[j] += v * wr[j];
      } else {
        pairs[idx].x = (unsigned)c; pairs[idx].y = __float_as_uint(v); idx++;
        if (c < 1000) vh += v; else if (c < 3000) v1s += v; else v2s += v;
      }
    }
    if (s >= 10000){
      const float* wrw = wW + (size_t)(s - 10000) * 8;
      #pragma unroll
      for (int j = 0; j < 8; j++) qr[j] = f2bf(wrw[j]);
      qr[8] = f2bf(1.0f);
    }
    #pragma unroll
    for (int j = 0; j < 8; j++) qr[9 + j] = f2bf(w8[j]);
    qr[17] = f2bf(cw); qr[18] = f2bf(vh); qr[19] = f2bf(v1s); qr[20] = f2bf(v2s);
    qr[21] = f2bf(s < 1000 ? 1.f : 0.f);
    qr[22] = f2bf((s >= 1000 && s < 3000) ? 1.f : 0.f);
    qr[23] = f2bf((s >= 3000 && s < 10000) ? 1.f : 0.f);
    float ep = (s >= 10000) ? C8f : (s < 1000 ? C21f : (s < 3000 ? C22f : C23f));
    ep += cw * C17f + vh * C18f + v1s * C19f + v2s * C20f;
    EP[s] = ep;
  } else {
    EP[s] = 0.f;
  }
  nsm[s] = idx;
  #pragma unroll
  for (int e = 0; e < 10; e++) cv[(size_t)s * 10 + e] = pairs[e];
  short8* qp = (short8*)(qbf + (size_t)s * 32);
  const short8* src = (const short8*)qr;
  qp[0] = src[0]; qp[1] = src[1]; qp[2] = src[2]; qp[3] = src[3];
}

// ---------------- fp32 -> bf16 conversion of everything (BN finalize inlined) ----------------
__global__ void convert_all(
  const float* __restrict__ x, const float* __restrict__ colacc,
  const float* __restrict__ gamma, const float* __restrict__ beta, unsigned short* __restrict__ xbn,
  const float* __restrict__ dw, unsigned short* __restrict__ dwb,
  const float* __restrict__ h1w, unsigned short* __restrict__ h1b,
  const float* __restrict__ h2w, unsigned short* __restrict__ h2b,
  const float* __restrict__ sh, const float* __restrict__ wh,
  const float* __restrict__ s11, const float* __restrict__ w11,
  const float* __restrict__ s21, const float* __restrict__ w21,
  const float* __restrict__ s31, const float* __restrict__ w31, unsigned short* __restrict__ wcat,
  const float* __restrict__ st1w2, unsigned short* __restrict__ st1b,
  const float* __restrict__ wt1w2, unsigned short* __restrict__ wt1b,
  const float* __restrict__ st2w2, unsigned short* __restrict__ st2b,
  const float* __restrict__ wt2w2, unsigned short* __restrict__ wt2b)
{
  size_t i = (size_t)blockIdx.x * 256 + threadIdx.x;
  const size_t o1 = 524288, o2 = o1 + 524288, o3 = o2 + 262144, o4 = o3 + 262144,
               o5 = o4 + 1199104, o6 = o5 + 256000, o7 = o6 + 256000, o8 = o7 + 224000,
               o9 = o8 + 224000;
  if (i < o1){
    int c = (int)(i & 1023);
    float mu = colacc[c] * (1.0f / 512.0f);
    float var = colacc[1024 + c] * (1.0f / 512.0f) - mu * mu;
    float sc = rsqrtf(var + 1e-5f) * gamma[c];
    float shv = beta[c] - mu * sc;
    xbn[i] = f2bf(x[i] * sc + shv);
  }
  else if (i < o2){ size_t l = i - o1; dwb[l] = f2bf(dw[l]); }
  else if (i < o3){ size_t l = i - o2; h1b[l] = f2bf(h1w[l]); }
  else if (i < o4){ size_t l = i - o3; h2b[l] = f2bf(h2w[l]); }
  else if (i < o5){
    size_t l = i - o4;
    float v;
    if (l < 513536) v = sh[l];
    else if (l < 1027072) v = wh[l - 513536];
    else if (l < 1092608) v = s11[l - 1027072];
    else if (l < 1158144) v = w11[l - 1092608];
    else if (l < 1174528) v = s21[l - 1158144];
    else if (l < 1190912) v = w21[l - 1174528];
    else if (l < 1195008) v = s31[l - 1190912];
    else v = w31[l - 1195008];
    wcat[l] = f2bf(v);
  }
  else if (i < o6){ size_t l = i - o5; st1b[l] = f2bf(st1w2[l]); }
  else if (i < o7){ size_t l = i - o6; wt1b[l] = f2bf(wt1w2[l]); }
  else if (i < o8){ size_t l = i - o7; st2b[l] = f2bf(st2w2[l]); }
  else if (i < o9){ size_t l = i - o8; wt2b[l] = f2bf(wt2w2[l]); }
}

// ---------------- MLP NT bf16 MFMA GEMM: C[m,n] = sum_k A[m,k]*B[n,k] -> bf16 ----------------
__global__ __launch_bounds__(256) void gemm_mlp(
  const unsigned short* __restrict__ A, int lda, const unsigned short* __restrict__ B,
  const float* __restrict__ bias, unsigned short* __restrict__ outB,
  int N, int K, int relu)
{
  int t = threadIdx.x; int wave = t >> 6; int L = t & 63; int quad = L >> 4; int l16 = L & 15;
  int mbase = blockIdx.y * 64 + wave * 16;
  int nb0 = blockIdx.x * 16;
  f32x4 acc = {0,0,0,0};
  int mrow = mbase + l16;
  const unsigned short* Ap = A + (size_t)mrow * lda + quad * 8;
  int nn = nb0 + l16;
  if (nn > N - 1) nn = N - 1;
  const unsigned short* Bp = B + (size_t)nn * K + quad * 8;
  for (int k0 = 0; k0 < K; k0 += 32){
    short8 a = *(const short8*)(Ap + k0);
    short8 b = *(const short8*)(Bp + k0);
    acc = __builtin_amdgcn_mfma_f32_16x16x32_bf16(a, b, acc, 0, 0, 0);
  }
  int n = nb0 + l16;
  if (n < N){
    float bv = bias ? bias[n] : 0.0f;
    #pragma unroll
    for (int r = 0; r < 4; r++){
      int m = mbase + quad * 4 + r;
      float v = acc[r] + bv;
      if (relu) v = fmaxf(v, 0.0f);
      outB[(size_t)m * N + n] = f2bf(v);
    }
  }
}

// ---------------- Zcat GEMM + head exp-sums + htcat + FUSED head transpose into smallT ----------
// smallT is bf16 (raw logits |v|<~2, bf16 err ~0.004 << absmax 0.125).
__global__ __launch_bounds__(256) void gemm_zcat(
  const unsigned short* __restrict__ A, const unsigned short* __restrict__ B,
  float* __restrict__ Zcat, unsigned short* __restrict__ htcat, float* __restrict__ sums6,
  unsigned short* __restrict__ smallT)
{
  const int N = ZCAT_COLS, K = 512;
  int t = threadIdx.x; int wave = t >> 6; int L = t & 63; int quad = L >> 4; int l16 = L & 15;
  int mbase = blockIdx.y * 64 + wave * 16;
  int nb0 = blockIdx.x * 16;
  f32x4 acc = {0,0,0,0};
  int mrow = mbase + l16;
  const unsigned short* Ap = A + (size_t)mrow * 512 + quad * 8;
  int nn = nb0 + l16;
  if (nn > N - 1) nn = N - 1;
  const unsigned short* Bp = B + (size_t)nn * K + quad * 8;
  for (int k0 = 0; k0 < K; k0 += 32){
    short8 a = *(const short8*)(Ap + k0);
    short8 b = *(const short8*)(Bp + k0);
    acc = __builtin_amdgcn_mfma_f32_16x16x32_bf16(a, b, acc, 0, 0, 0);
  }
  bool doEps = (nb0 < 2006);
  __shared__ float sacc[64][2];
  __shared__ float tile[16][65];
  if (doEps){
    for (int e = threadIdx.x; e < 128; e += 256) ((float*)sacc)[e] = 0.f;
    __syncthreads();
  }
  int c = nb0 + l16;
  #pragma unroll
  for (int r = 0; r < 4; r++){
    int m = mbase + quad * 4 + r;
    float v = acc[r];
    if (c < N){
      bool zkeep = (c >= 1000 && c < 1003) || (c >= 2003 && c < 2006) || (c >= 2326);
      if (zkeep) Zcat[(size_t)m * ZCAT_COLS + c] = v;
      if (c >= 2006) htcat[(size_t)m * 336 + (c - 2006)] = f2bf(v);
    }
    if (doEps){
      float e0 = (c < 1003) ? __expf(v) : 0.f;
      float e1 = (c >= 1003 && c < 2006) ? __expf(v) : 0.f;
      #pragma unroll
      for (int d = 8; d > 0; d >>= 1){ e0 += __shfl_xor(e0, d); e1 += __shfl_xor(e1, d); }
      if (l16 == 0){
        int mr = wave * 16 + quad * 4 + r;
        if (e0 != 0.f) atomicAdd(&sacc[mr][0], e0);
        if (e1 != 0.f) atomicAdd(&sacc[mr][1], e1);
      }
    }
  }
  bool doT = (nb0 < 2003);   // block-uniform
  if (doT){
    #pragma unroll
    for (int r = 0; r < 4; r++)
      tile[l16][wave * 16 + quad * 4 + r] = acc[r];
    __syncthreads();
    int tlo = t & 63, thi = t >> 6;
    int m0 = blockIdx.y * 64;
    #pragma unroll
    for (int p = 0; p < 4; p++){
      int cl = thi + p * 4;
      int cg = nb0 + cl;
      int row = -1;
      if (cg < 1000) row = cg;                              // S-side head
      else if (cg >= 1003 && cg < 2003) row = 10000 + (cg - 1003);  // W-side head
      if (row >= 0) smallT[(size_t)row * 512 + m0 + tlo] = f2bf(tile[cl][tlo]);
    }
  }
  if (doEps){
    __syncthreads();
    int tt = threadIdx.x;
    if (tt < 128){
      int mr = tt >> 1;
      float v = sacc[mr][tt & 1];
      if (v != 0.f) atomicAdd(&sums6[(blockIdx.y * 64 + mr) * 8 + (tt & 1)], v);
    }
  }
}

// ---------------- merged tail GEMMs + exp-sums + FUSED transposed bf16 write into smallT ----------
// Flattened grid: bx in [0,32) zi=0; [32,64) zi=1; [64,174) zi=2; [174,284) zi=3 (no dead blocks).
// smallT row bases: z1S->1000, z1W->11000, z2S->3000, z2W->13000.
__global__ __launch_bounds__(256) void gemm_tail(
  const unsigned short* __restrict__ htcat,
  const unsigned short* __restrict__ b0, const unsigned short* __restrict__ b1,
  const unsigned short* __restrict__ b2, const unsigned short* __restrict__ b3,
  unsigned short* __restrict__ smallT, float* __restrict__ sums6)
{
  int bx = blockIdx.x;
  int zi, nbx;
  if (bx < 32){ zi = 0; nbx = bx; }
  else if (bx < 64){ zi = 1; nbx = bx - 32; }
  else if (bx < 174){ zi = 2; nbx = bx - 64; }
  else { zi = 3; nbx = bx - 174; }
  int N = (zi < 2) ? 2000 : 7000;
  int K = (zi < 2) ? 128 : 32;
  int aoff = (zi == 0) ? 0 : (zi == 1) ? 128 : (zi == 2) ? 256 : 288;
  int rowbase = (zi == 0) ? 1000 : (zi == 1) ? 11000 : (zi == 2) ? 3000 : 13000;
  const unsigned short* B = (zi == 0) ? b0 : (zi == 1) ? b1 : (zi == 2) ? b2 : b3;
  int nb0 = nbx * 64;
  int t = threadIdx.x; int wave = t >> 6; int L = t & 63; int quad = L >> 4; int l16 = L & 15;
  int mbase = blockIdx.y * 64 + wave * 16;
  f32x4 acc[4] = {{0,0,0,0},{0,0,0,0},{0,0,0,0},{0,0,0,0}};
  int mrow = mbase + l16;
  const unsigned short* Ap = htcat + (size_t)mrow * 336 + aoff + quad * 8;
  const unsigned short* Bp[4];
  #pragma unroll
  for (int j = 0; j < 4; j++){
    int n = nb0 + j * 16 + l16;
    if (n > N - 1) n = N - 1;
    Bp[j] = B + (size_t)n * K + quad * 8;
  }
  for (int k0 = 0; k0 < K; k0 += 32){
    short8 a = *(const short8*)(Ap + k0);
    #pragma unroll
    for (int j = 0; j < 4; j++){
      short8 b = *(const short8*)(Bp[j] + k0);
      acc[j] = __builtin_amdgcn_mfma_f32_16x16x32_bf16(a, b, acc[j], 0, 0, 0);
    }
  }
  __shared__ float sacc[64];
  __shared__ float tile[64][65];
  for (int e = threadIdx.x; e < 64; e += 256) sacc[e] = 0.f;
  __syncthreads();
  #pragma unroll
  for (int j = 0; j < 4; j++){
    int n = nb0 + j * 16 + l16;
    #pragma unroll
    for (int r = 0; r < 4; r++){
      int mloc = wave * 16 + quad * 4 + r;
      float v = acc[j][r];
      tile[j * 16 + l16][mloc] = v;
      float e = (n < N) ? __expf(v) : 0.f;
      #pragma unroll
      for (int d = 8; d > 0; d >>= 1) e += __shfl_xor(e, d);
      if (l16 == 0) atomicAdd(&sacc[mloc], e);
    }
  }
  __syncthreads();
  // transposed write-out: 64 c-rows x 64 m-cols, coalesced along m (bf16)
  int tlo = t & 63, thi = t >> 6;
  int m0 = blockIdx.y * 64 + tlo;
  #pragma unroll
  for (int p = 0; p < 16; p++){
    int cl = thi + p * 4;
    int cg = nb0 + cl;
    if (cg < N) smallT[(size_t)(rowbase + cg) * 512 + m0] = f2bf(tile[cl][tlo]);
  }
  if (threadIdx.x < 64){
    float v = sacc[threadIdx.x];
    atomicAdd(&sums6[(blockIdx.y * 64 + threadIdx.x) * 8 + 2 + zi], v);
  }
}

// ---------------- per-n finals -> rbf (2 blocks, one n per thread) ----------------
__global__ __launch_bounds__(256) void finals_kernel(const float* __restrict__ Zcat,
                                                     const float* __restrict__ sums6,
                                                     const float* __restrict__ mom,
                                                     unsigned short* __restrict__ rbf){
  int n = blockIdx.x * 256 + threadIdx.x;
  if (n >= 512) return;
  {
    const float* zrow = Zcat + (size_t)n * ZCAT_COLS;
    float lseHS = __logf(sums6[n * 8 + 0]), lseHW = __logf(sums6[n * 8 + 1]);
    float lse1S = __logf(sums6[n * 8 + 2]), lse1W = __logf(sums6[n * 8 + 3]);
    float lse2S = __logf(sums6[n * 8 + 4]), lse2W = __logf(sums6[n * 8 + 5]);
    float uS[8], uW[8];
    #pragma unroll
    for (int j = 0; j < 8; j++){ uS[j] = zrow[2326 + j]; uW[j] = zrow[2334 + j]; }
    const float* mS = mom; const float* mW = mom + 72;
    float d1 = 0.f, d2 = 0.f, e1 = 0.f, e2 = 0.f;
    #pragma unroll
    for (int a = 0; a < 8; a++){
      d1 += uS[a] * mS[a]; e1 += uW[a] * mW[a];
      #pragma unroll
      for (int b = 0; b < 8; b++){
        d2 += uS[a] * uS[b] * mS[8 + a * 8 + b];
        e2 += uW[a] * uW[b] * mW[8 + a * 8 + b];
      }
    }
    float lse3S = __logf((float)J_SLM + d1 + 0.5f * d2);
    float lse3W = __logf((float)J_WSD + e1 + 0.5f * e2);
    float C3w = (zrow[2005] - lseHW) - lse3W;
    float C3s = (zrow[1002] - lseHS) - lse3S;
    float A1s = zrow[1000] - lseHS - lse1S;
    float A2s = zrow[1001] - lseHS - lse2S;
    float A1w = zrow[2003] - lseHW - lse1W;
    float A2w = zrow[2004] - lseHW - lse2W;
    unsigned short* rr = rbf + n * 32;
    #pragma unroll
    for (int j = 0; j < 8; j++){ rr[j] = f2bf(uW[j]); rr[9 + j] = f2bf(uS[j]); }
    rr[8]  = f2bf(C3w - C8f);
    rr[17] = f2bf(C3s - C17f);
    rr[18] = f2bf(-lseHS - C18f);
    rr[19] = f2bf(A1s - C19f);
    rr[20] = f2bf(A2s - C20f);
    rr[21] = f2bf(-lseHW - C21f);
    rr[22] = f2bf(A1w - C22f);
    rr[23] = f2bf(A2w - C23f);
    #pragma unroll
    for (int j = 24; j < 32; j++) rr[j] = 0;
  }
}

// ---------------- the big output kernel ----------------
// Grid (16,460), i=2: 7360 blocks (~29 blocks/CU of work at ~8 resident) for deeper
// latency hiding; n-split on blockIdx.x (fastest) keeps qbf/cv/EP L3-hot across the
// 16 blocks sharing a sense window. afrags preloaded (static unroll, no scratch).
// LDS-staged epilogue: aligned float4 drain (R7: −18.5us vs scalar stores).
__global__ __launch_bounds__(256, 4) void final2(
  const unsigned short* __restrict__ rbf, const unsigned short* __restrict__ qbf,
  const float* __restrict__ EP, const int* __restrict__ nsm,
  const uint2* __restrict__ cv, const unsigned short* __restrict__ smallT,
  float* __restrict__ out)
{
  int t = threadIdx.x; int wave = t >> 6; int L = t & 63; int quad = L >> 4; int l16 = L & 15;
  int sbase = blockIdx.y * 256 + wave * 64;
  int nbase = blockIdx.x * 32;
  __shared__ float ot[16][260];   // 16 n-rows x 256 s-cols (+4 pad): 16.6KB, 8 blocks/CU ok
  short8 bfrag[4]; float ep[4]; int cnt[4]; int kmax[4];
  int ccol[4][3]; float cval[4][3];
  #pragma unroll
  for (int j = 0; j < 4; j++){
    int s = sbase + j * 16 + l16;
    bfrag[j] = *(const short8*)(qbf + (size_t)s * 32 + quad * 8);
    ep[j] = EP[s]; cnt[j] = nsm[s];
    #pragma unroll
    for (int k = 0; k < 3; k++){
      uint2 e = cv[(size_t)s * 10 + k];
      ccol[j][k] = (int)e.x; cval[j][k] = __uint_as_float(e.y);
    }
    int kw = cnt[j];
    #pragma unroll
    for (int d = 32; d > 0; d >>= 1){ int o = __shfl_xor(kw, d); kw = (o > kw) ? o : kw; }
    kmax[j] = __builtin_amdgcn_readfirstlane(kw);
  }
  // preload both afrags (static indexing)
  short8 afrag0 = *(const short8*)(rbf + (size_t)(nbase + l16) * 32 + quad * 8);
  short8 afrag1 = *(const short8*)(rbf + (size_t)(nbase + 16 + l16) * 32 + quad * 8);
  int trow = t >> 4;               // 0..15 (drain row)
  int tcol = (t & 15) * 16;        // 0..240 step 16 (drain col base)
  int sblk = blockIdx.y * 256;     // block s-window base
  #pragma unroll
  for (int i = 0; i < 2; i++){
    int n0 = nbase + i * 16;
    short8 afrag = (i == 0) ? afrag0 : afrag1;
    int nq = n0 + quad * 4;
    #pragma unroll
    for (int j = 0; j < 4; j++){
      f32x4 acc = {0.f, 0.f, 0.f, 0.f};
      acc = __builtin_amdgcn_mfma_f32_16x16x32_bf16(afrag, bfrag[j], acc, 0, 0, 0);
      f32x4 res = acc + ep[j];
      #pragma unroll
      for (int k = 0; k < 3; k++){
        if (k < kmax[j]){                 // wave-uniform skip
          if (k < cnt[j]){                // per-lane mask
            ushort4v q = *(const ushort4v*)(smallT + ((size_t)ccol[j][k] << 9) + nq);
            f32x4 sv = {bf2f(q[0]), bf2f(q[1]), bf2f(q[2]), bf2f(q[3])};
            res += cval[j][k] * sv;
          }
        }
      }
      if (kmax[j] >= 4){                  // rare overflow path (P ~ 1%)
        int s = sbase + j * 16 + l16;
        for (int k = 3; k < 9; k++){
          if (k < cnt[j]){
            uint2 e = cv[(size_t)s * 10 + k];
            ushort4v q = *(const ushort4v*)(smallT + ((size_t)e.x << 9) + nq);
            f32x4 sv = {bf2f(q[0]), bf2f(q[1]), bf2f(q[2]), bf2f(q[3])};
            res += __uint_as_float(e.y) * sv;
          }
        }
      }
      // stage into LDS: row = local n (quad*4+r), col = wave*64 + j*16 + l16
      int lc = wave * 64 + j * 16 + l16;
      #pragma unroll
      for (int r = 0; r < 4; r++)
        ot[quad * 4 + r][lc] = res[r];
    }
    __syncthreads();
    // drain: thread t writes row (t>>4), 4 x float4 at cols (t&15)*16 + cc*4
    {
      size_t rowoff = (size_t)(n0 + trow) * S_TOT;
      #pragma unroll
      for (int cc = 0; cc < 4; cc++){
        int scol = sblk + tcol + cc * 4;
        if (scol < S_TOT){
          f32x4 v = *(const f32x4*)&ot[trow][tcol + cc * 4];
          *(f32x4*)&out[rowoff + scol] = v;
        }
      }
    }
    __syncthreads();
  }
}

extern "C" void kernel_launch(void* const* d_in, const int* in_sizes, int n_in,
                              void* d_out, int out_size, void* d_ws, size_t ws_size,
                              hipStream_t stream)
{
  const float* x      = (const float*)d_in[0];
  const float* gamma  = (const float*)d_in[1];
  const float* beta   = (const float*)d_in[2];
  const float* dw     = (const float*)d_in[3];
  const float* db     = (const float*)d_in[4];
  const float* h1w    = (const float*)d_in[5];
  const float* h1bias = (const float*)d_in[6];
  const float* h2w    = (const float*)d_in[7];
  const float* h2bias = (const float*)d_in[8];
  const float* whead  = (const float*)d_in[9];
  const float* wt1w1  = (const float*)d_in[10];
  const float* wt1w2  = (const float*)d_in[11];
  const float* wt2w1  = (const float*)d_in[12];
  const float* wt2w2  = (const float*)d_in[13];
  const float* wt3w1  = (const float*)d_in[14];
  const float* wt3w2  = (const float*)d_in[15];
  const float* shead  = (const float*)d_in[16];
  const float* st1w1  = (const float*)d_in[17];
  const float* st1w2  = (const float*)d_in[18];
  const float* st2w1  = (const float*)d_in[19];
  const float* st2w2  = (const float*)d_in[20];
  const float* st3w1  = (const float*)d_in[21];
  const float* st3w2  = (const float*)d_in[22];
  const float* svv    = (const float*)d_in[23];
  const int*   svc    = (const int*)d_in[24];
  float* out = (float*)d_out;

  char* wsb = (char*)d_ws; size_t off = 0;
  auto alloc = [&](size_t bytes) -> void* {
    void* p = wsb + off;
    off = (off + bytes + 255) & ~(size_t)255;
    return p;
  };
  // zero-init region (one memset): colacc | mom | sums6
  float* colacc = (float*)alloc(2048 * 4);
  float* mom    = (float*)alloc(2 * 72 * 4);
  float* sums6  = (float*)alloc(512 * 8 * 4);
  size_t zero_bytes = ((char*)sums6 - (char*)colacc) + 512 * 8 * 4;

  unsigned short* xbn   = (unsigned short*)alloc((size_t)512 * 1024 * 2);
  unsigned short* dwb   = (unsigned short*)alloc((size_t)512 * 1024 * 2);
  unsigned short* h1b   = (unsigned short*)alloc((size_t)512 * 512 * 2);
  unsigned short* h2b   = (unsigned short*)alloc((size_t)512 * 512 * 2);
  unsigned short* wcat  = (unsigned short*)alloc((size_t)ZCAT_COLS * 512 * 2);
  unsigned short* st1b  = (unsigned short*)alloc((size_t)2000 * 128 * 2);
  unsigned short* wt1b  = (unsigned short*)alloc((size_t)2000 * 128 * 2);
  unsigned short* st2b  = (unsigned short*)alloc((size_t)7000 * 32 * 2);
  unsigned short* wt2b  = (unsigned short*)alloc((size_t)7000 * 32 * 2);
  unsigned short* a_bf  = (unsigned short*)alloc((size_t)512 * 512 * 2);
  unsigned short* t_bf  = (unsigned short*)alloc((size_t)512 * 512 * 2);
  unsigned short* h_bf  = (unsigned short*)alloc((size_t)512 * 512 * 2);
  unsigned short* htcat = (unsigned short*)alloc((size_t)512 * 336 * 2);
  float* Zcat  = (float*)alloc((size_t)512 * ZCAT_COLS * 4);
  unsigned short* rbf = (unsigned short*)alloc((size_t)512 * 32 * 2);
  unsigned short* smallT = (unsigned short*)alloc((size_t)20000 * 512 * 2);
  unsigned short* qbf = (unsigned short*)alloc((size_t)S_PAD * 32 * 2);
  float* EP  = (float*)alloc((size_t)S_PAD * 4);
  int*   nsm = (int*)alloc((size_t)S_PAD * 4);
  uint2* cv  = (uint2*)alloc((size_t)S_PAD * 10 * 8);

  (void)in_sizes; (void)n_in; (void)out_size; (void)ws_size;

  hipMemsetAsync(colacc, 0, zero_bytes, stream);
  prep_kernel<<<588, 256, 0, stream>>>(x, colacc, st3w2, wt3w2, mom,
                                       svc, svv, qbf, EP, nsm, cv);
  convert_all<<<14578, 256, 0, stream>>>(
      x, colacc, gamma, beta, xbn, dw, dwb, h1w, h1b, h2w, h2b,
      shead, whead, st1w1, wt1w1, st2w1, wt2w1, st3w1, wt3w1, wcat,
      st1w2, st1b, wt1w2, wt1b, st2w2, st2b, wt2w2, wt2b);

  gemm_mlp<<<dim3(32, 8), 256, 0, stream>>>(xbn, 1024, dwb, db, a_bf, 512, 1024, 0);
  gemm_mlp<<<dim3(32, 8), 256, 0, stream>>>(a_bf, 512, h1b, h1bias, t_bf, 512, 512, 1);
  gemm_mlp<<<dim3(32, 8), 256, 0, stream>>>(t_bf, 512, h2b, h2bias, h_bf, 512, 512, 0);
  gemm_zcat<<<dim3(147, 8), 256, 0, stream>>>(h_bf, wcat, Zcat, htcat, sums6, smallT);
  gemm_tail<<<dim3(284, 8), 256, 0, stream>>>(htcat, st1b, wt1b, st2b, wt2b,
                                              smallT, sums6);
  finals_kernel<<<2, 256, 0, stream>>>(Zcat, sums6, mom, rbf);
  final2<<<dim3(16, 460), 256, 0, stream>>>(rbf, qbf, EP, nsm, cv, smallT, out);
}